// Round 2
// baseline (521.463 us; speedup 1.0000x reference)
//
#include <hip/hip_runtime.h>

#define CC   256
#define HWS  4096
#define MPAD 4160   // 65*64, rows >= 4097 zero-padded
#define NB   4
#define NTIL 65

typedef __attribute__((ext_vector_type(8))) short   short8;
typedef __attribute__((ext_vector_type(4))) float   floatx4;

static __device__ __forceinline__ short8 ld8(const unsigned short* p) {
  return *(const short8*)p;
}
static __device__ __forceinline__ void st8(unsigned short* p, short8 v) {
  *(short8*)p = v;
}
static __device__ __forceinline__ unsigned short f2b(float x) {
  union { float f; unsigned u; } v; v.f = x;
  unsigned r = v.u + 0x7FFFu + ((v.u >> 16) & 1u);
  return (unsigned short)(r >> 16);
}
static __device__ __forceinline__ float b2f(unsigned short x) {
  union { unsigned u; float f; } v; v.u = ((unsigned)x) << 16;
  return v.f;
}
// async global->LDS, 16B per lane, LDS dest = uniform base + lane*16
static __device__ __forceinline__ void gl_lds16(const unsigned short* g, unsigned short* l) {
  __builtin_amdgcn_global_load_lds(
      (const __attribute__((address_space(1))) unsigned int*)g,
      (__attribute__((address_space(3))) unsigned int*)l, 16, 0, 0);
}

// ---- St[d][c] = sim[c][d] (bf16), Vw[d][c] = v_w[d][c] (bf16)
__global__ void prep_mats(const float* __restrict__ sim, const float* __restrict__ vw,
                          unsigned short* __restrict__ St, unsigned short* __restrict__ Vw) {
  int dd = blockIdx.x, c = threadIdx.x;
  St[dd*CC + c] = f2b(sim[c*CC + dd]);
  Vw[dd*CC + c] = f2b(vw[dd*CC + c]);
}

// ---- colb[b][m]: additive column bias. m<HWS: (mask-1)*1e9; m==4096: 0; pad: -3e38
__global__ void colb_kernel(const float* __restrict__ mask, float* __restrict__ colb) {
  int b = blockIdx.x, tid = threadIdx.x;
  for (int m = tid; m < MPAD; m += 256) {
    float v;
    if (m < HWS)      v = (mask[b*HWS + m] - 1.0f) * 1e9f;
    else if (m == HWS) v = 0.0f;
    else               v = -3.0e38f;
    colb[b*MPAD + m] = v;
  }
}

// ---- Kt[b][m][d] = bf16(concat[b][d][m]); m==4096 -> 1.2*exe; m>4096 -> 0
__global__ void build_kt(const float* __restrict__ img, const float* __restrict__ exe,
                         unsigned short* __restrict__ Kt) {
  int b = blockIdx.x, mt = blockIdx.y, dt = blockIdx.z;
  int tid = threadIdx.x;
  int m0 = mt*64, d0 = dt*64;
  if (mt == 64) {
    for (int i = 0; i < 16; ++i) {
      int m = m0 + (tid>>6) + i*4;
      int d = d0 + (tid&63);
      unsigned short v = 0;
      if (m == 4096) v = f2b(1.2f * exe[b*CC + d]);
      Kt[((size_t)b*MPAD + m)*CC + d] = v;
    }
    return;
  }
  __shared__ float tile[64][65];
  for (int i = 0; i < 16; ++i) {
    int dl = (tid>>6) + i*4, ml = tid&63;
    tile[dl][ml] = img[((size_t)b*CC + d0+dl)*HWS + m0+ml];
  }
  __syncthreads();
  for (int i = 0; i < 16; ++i) {
    int ml = (tid>>6) + i*4, dl = tid&63;
    Kt[((size_t)b*MPAD + m0+ml)*CC + d0+dl] = f2b(tile[dl][ml]);
  }
}

// ---- mode 0: T[b][n][d] = bf16( sum_c Kt[n][c]*St[d][c] )           (rows < HWS)
// ---- mode 1: Vbt[b][d][m] = bf16( sum_c Kt[m][c]*Vw[d][c] )         (rows < MPAD)
__global__ __launch_bounds__(256) void gemm_small(const unsigned short* __restrict__ Kt,
    const unsigned short* __restrict__ Bm, unsigned short* __restrict__ Tout,
    unsigned short* __restrict__ Vbt, int mode) {
  int b  = blockIdx.x;
  int r0 = blockIdx.y*64 + (threadIdx.x>>6)*16;
  int c0 = blockIdx.z*64;
  int lane = threadIdx.x & 63;
  int lo = lane & 15, hi = lane >> 4;
  floatx4 acc[4] = {};
  const unsigned short* arow = Kt + ((size_t)b*MPAD + r0 + lo)*CC + hi*8;
#pragma unroll
  for (int k = 0; k < 8; ++k) {
    short8 af = ld8(arow + k*32);
#pragma unroll
    for (int t = 0; t < 4; ++t) {
      short8 bf = ld8(Bm + (size_t)(c0 + t*16 + lo)*CC + k*32 + hi*8);
      acc[t] = __builtin_amdgcn_mfma_f32_16x16x32_bf16(af, bf, acc[t], 0, 0, 0);
    }
  }
  if (mode == 0) {
#pragma unroll
    for (int t = 0; t < 4; ++t)
#pragma unroll
      for (int r = 0; r < 4; ++r) {
        int n = r0 + hi*4 + r, dd = c0 + t*16 + lo;
        Tout[((size_t)b*HWS + n)*CC + dd] = f2b(acc[t][r]);
      }
  } else {
#pragma unroll
    for (int t = 0; t < 4; ++t)
#pragma unroll
      for (int r = 0; r < 4; ++r) {
        int m = r0 + hi*4 + r, dd = c0 + t*16 + lo;
        Vbt[((size_t)b*CC + dd)*MPAD + m] = f2b(acc[t][r]);
      }
  }
}

// ---- reorder K and V into MFMA-fragment-major order, 1KB per instruction slot.
__global__ __launch_bounds__(256) void reorder_kv(const unsigned short* __restrict__ Kt,
    const unsigned short* __restrict__ Vbt, unsigned short* __restrict__ Kf,
    unsigned short* __restrict__ Vf) {
  int b = blockIdx.x, mt = blockIdx.y;
  int m0 = mt*64;
  int tid = threadIdx.x;
  int w = tid >> 6, lane = tid & 63;
  int lo = lane & 15, hi = lane >> 4;
  size_t tile = (size_t)(b*NTIL + mt)*16384;
  unsigned short* kf = Kf + tile;
  unsigned short* vf = Vf + tile;
  const unsigned short* ktb = Kt  + (size_t)b*MPAD*CC;
  const unsigned short* vtb = Vbt + (size_t)b*CC*MPAD;
#pragma unroll
  for (int i = 0; i < 8; ++i) {
    int s = i*4 + w;
    { // K slot
      int k = s >> 2, t = s & 3;
      short8 v = ld8(ktb + (size_t)(m0 + t*16 + lo)*CC + k*32 + hi*8);
      st8(kf + s*512 + lane*8, v);
    }
    { // V slot
      int h = s >> 4, t = s & 15;
      short8 v = ld8(vtb + (size_t)(t*16 + lo)*MPAD + m0 + h*32 + hi*8);
      st8(vf + s*512 + lane*8, v);
    }
  }
}

// ---- score mimicry of np/BLAS fp32 T-path, sequential FMA everywhere
__global__ __launch_bounds__(256) void scores_kernel(const float* __restrict__ img,
    const float* __restrict__ sim, const float* __restrict__ exe,
    float* __restrict__ score32) {
  int b = blockIdx.x, n0 = blockIdx.y*16;
  int d = threadIdx.x;
  __shared__ float U[16][257];        // U[nl][c] = img[b, c, n0+nl]
  __shared__ float R[16][256];        // T32[nl][d]
  __shared__ float E[256];
  for (int idx = threadIdx.x; idx < 16*256; idx += 256) {
    int nl = idx & 15, c = idx >> 4;
    U[nl][c] = img[((size_t)b*CC + c)*HWS + n0 + nl];
  }
  E[d] = 1.2f * exe[b*CC + d];
  __syncthreads();
  float acc[16];
#pragma unroll
  for (int nl = 0; nl < 16; ++nl) acc[nl] = 0.f;
  for (int c = 0; c < CC; ++c) {
    float s_cd = sim[c*CC + d];
#pragma unroll
    for (int nl = 0; nl < 16; ++nl) acc[nl] = fmaf(U[nl][c], s_cd, acc[nl]);
  }
#pragma unroll
  for (int nl = 0; nl < 16; ++nl) R[nl][d] = acc[nl];
  __syncthreads();
  if (d < 16) {
    float s = 0.f;
    for (int dd = 0; dd < CC; ++dd) s = fmaf(R[d][dd], E[dd], s);
    score32[b*HWS + n0 + d] = s;
  }
}

// ---- top-150 via exact radix-select on distinct 44-bit keys + bitonic-256 sort.
__global__ __launch_bounds__(64) void select_kernel(const float* __restrict__ scores,
                                                    int* __restrict__ qids) {
  int b = blockIdx.x, lane = threadIdx.x;
  __shared__ float sc[HWS];
  __shared__ unsigned long long kx[HWS];
  __shared__ unsigned long long list[256];
  __shared__ unsigned int hist[256];
  __shared__ unsigned int st[4];
  __shared__ unsigned long long sh_base;

  const floatx4* s4 = (const floatx4*)(scores + (size_t)b*HWS);
  floatx4* c4 = (floatx4*)sc;
#pragma unroll
  for (int i = 0; i < 16; ++i) c4[i*64 + lane] = s4[i*64 + lane];
  __syncthreads();

  for (int i = 0; i < 64; ++i) {
    int idx = i*64 + lane;
    int y = i, x = lane;
    float c0 = sc[idx];
    float v = c0;
    if (y >= 1 && y <= 62 && x >= 1 && x <= 62) {
      bool ismax = (c0 > sc[idx-64]) && (c0 >= sc[idx+64]) &&
                   (c0 > sc[idx-1])  && (c0 >= sc[idx+1]);
      if (!ismax) v = c0 - 1e9f;
    }
    unsigned u = __float_as_uint(v);
    u = (u & 0x80000000u) ? ~u : (u | 0x80000000u);
    kx[idx] = (((unsigned long long)u) << 12) | (unsigned long long)(4095 - idx);
  }
  __syncthreads();

  unsigned long long base = 0;
  unsigned int need = 150, C = 0;
  for (int s = 36; s >= 4; s -= 8) {
    for (int i = lane; i < 256; i += 64) hist[i] = 0;
    __syncthreads();
    unsigned long long pref = base >> (s + 8);
    for (int i = 0; i < 64; ++i) {
      unsigned long long k = kx[i*64 + lane];
      if ((k >> (s + 8)) == pref) atomicAdd(&hist[(unsigned)(k >> s) & 255u], 1u);
    }
    __syncthreads();
    if (lane == 0) {
      unsigned cum = 0; int B = 0;
      for (int bin = 255; bin >= 0; --bin) {
        cum += hist[bin];
        if (cum >= need) { B = bin; break; }
      }
      st[0] = (150u - need) + cum;
      st[1] = need - (cum - hist[B]);
      sh_base = base | ((unsigned long long)B << s);
    }
    __syncthreads();
    C = st[0]; need = st[1]; base = sh_base;
    if (C <= 256u) break;
  }

  if (lane == 0) st[2] = 0;
  __syncthreads();
  for (int i = 0; i < 64; ++i) {
    unsigned long long k = kx[i*64 + lane];
    if (k >= base) {
      unsigned p = atomicAdd(&st[2], 1u);
      list[p] = k;
    }
  }
  __syncthreads();
  for (int i = lane; i < 256; i += 64) if (i >= (int)C) list[i] = 0ull;
  __syncthreads();

  for (int kk = 2; kk <= 256; kk <<= 1) {
    for (int j = kk >> 1; j > 0; j >>= 1) {
#pragma unroll
      for (int tt = 0; tt < 2; ++tt) {
        int t = lane + tt*64;
        int i2 = ((t & ~(j - 1)) << 1) | (t & (j - 1));
        int p2 = i2 | j;
        bool desc = ((i2 & kk) == 0);
        unsigned long long a = list[i2], c = list[p2];
        bool sw = desc ? (a < c) : (a > c);
        if (sw) { list[i2] = c; list[p2] = a; }
      }
      __syncthreads();
    }
  }

  for (int q = lane; q < 150; q += 64)
    qids[b*150 + q] = 4095 - (int)(list[q] & 0xFFFull);
}

// ---- fused flash attention v6: LDS-shared K/V, 32 Q-rows per wave.
//      Round-1 counters showed v5 at 82% of the L2 ceiling (each of 4 waves
//      register-streamed the full 64KB tile-pair: 4.26 GB L2 reads). v6 stages
//      each tile-pair into double-buffered LDS (128KB) via global_load_lds
//      (L2 traffic /4) and gives each wave TWO 16-row fragments so each LDS
//      fragment read feeds two MFMAs (LDS traffic /2 per Q-row). Block = 2
//      waves x 32 rows = 64 rows; grid stays 256 = 1 block/CU. Fixed-max
//      softmax unchanged -> arithmetic bit-identical to v5.
__global__ __launch_bounds__(128, 1) void flash_kernel(
    const unsigned short* __restrict__ Tb, const unsigned short* __restrict__ Kt,
    const unsigned short* __restrict__ Kf, const unsigned short* __restrict__ Vf,
    const float* __restrict__ mask, const float* __restrict__ colb,
    const float* __restrict__ img, float* __restrict__ out0) {
  int blk = blockIdx.x;                       // 256 blocks
  int b   = (blk & 7) >> 1;                   // batch pinned to XCD pair
  int g   = ((blk >> 3) << 1) | (blk & 1);    // n-group [0,64)
  int bn0 = g << 6;
  int tid = threadIdx.x;
  int wave = tid >> 6, lane = tid & 63;
  int lo = lane & 15, hi = lane >> 4;
  int n0 = bn0 + wave*32;                     // this wave's 32 Q-rows

  __shared__ unsigned short kvK[2][16384];    // 2 x 32KB K tiles
  __shared__ unsigned short kvV[2][16384];    // 2 x 32KB V tiles
  __shared__ unsigned short pbuf[2][1152];    // per-wave P / M-exchange / epilogue
  unsigned short* plw = &pbuf[wave][0];

  const unsigned short* kfb = Kf + (size_t)b*NTIL*16384;
  const unsigned short* vfb = Vf + (size_t)b*NTIL*16384;

  // stage tile 0 into buffer 0 (split across the 2 waves)
#pragma unroll
  for (int i = 0; i < 16; ++i) {
    int s = wave*16 + i;
    gl_lds16(kfb + s*512 + lane*8, &kvK[0][s*512]);
    gl_lds16(vfb + s*512 + lane*8, &kvV[0][s*512]);
  }

  // Q fragments for this wave's two row-groups
  short8 q0[8], q1[8];
  const unsigned short* tb0 = Tb + ((size_t)b*HWS + n0 + lo)*CC + hi*8;
#pragma unroll
  for (int k = 0; k < 8; ++k) { q0[k] = ld8(tb0 + k*32); q1[k] = ld8(tb0 + 16*CC + k*32); }

  const float* mk = mask + b*HWS;

  // ---- prologue: diag and exe dots (fp32), fixed row max M = pick + 2
  float crb0[4], Msub0[4], crb1[4], Msub1[4];
  {
    const unsigned short* kep = Kt + ((size_t)b*MPAD + HWS)*CC + hi*8;
    // row-group 0
    float ddot = 0.f, edot = 0.f;
    const unsigned short* kdp = Kt + ((size_t)b*MPAD + n0 + lo)*CC + hi*8;
#pragma unroll
    for (int k = 0; k < 8; ++k) {
      short8 kd = ld8(kdp + k*32);
      short8 ke = ld8(kep + k*32);
#pragma unroll
      for (int j = 0; j < 8; ++j) {
        float qf = b2f((unsigned short)q0[k][j]);
        ddot = fmaf(qf, b2f((unsigned short)kd[j]), ddot);
        edot = fmaf(qf, b2f((unsigned short)ke[j]), edot);
      }
    }
    ddot += __shfl_xor(ddot, 16); ddot += __shfl_xor(ddot, 32);
    edot += __shfl_xor(edot, 16); edot += __shfl_xor(edot, 32);
    float Mrow = ((mk[n0 + lo] == 1.0f) ? ddot : edot) + 2.0f;
    float* fM = (float*)plw;
    fM[lo] = Mrow;
#pragma unroll
    for (int r = 0; r < 4; ++r) {
      Msub0[r] = fM[hi*4 + r];
      crb0[r]  = (mk[n0 + hi*4 + r] - 1.0f)*1e9f - Msub0[r];
    }
    // row-group 1
    ddot = 0.f; edot = 0.f;
    const unsigned short* kdp1 = Kt + ((size_t)b*MPAD + n0 + 16 + lo)*CC + hi*8;
#pragma unroll
    for (int k = 0; k < 8; ++k) {
      short8 kd = ld8(kdp1 + k*32);
      short8 ke = ld8(kep + k*32);
#pragma unroll
      for (int j = 0; j < 8; ++j) {
        float qf = b2f((unsigned short)q1[k][j]);
        ddot = fmaf(qf, b2f((unsigned short)kd[j]), ddot);
        edot = fmaf(qf, b2f((unsigned short)ke[j]), edot);
      }
    }
    ddot += __shfl_xor(ddot, 16); ddot += __shfl_xor(ddot, 32);
    edot += __shfl_xor(edot, 16); edot += __shfl_xor(edot, 32);
    float Mrow1 = ((mk[n0 + 16 + lo] == 1.0f) ? ddot : edot) + 2.0f;
    fM[lo] = Mrow1;
#pragma unroll
    for (int r = 0; r < 4; ++r) {
      Msub1[r] = fM[hi*4 + r];
      crb1[r]  = (mk[n0 + 16 + hi*4 + r] - 1.0f)*1e9f - Msub1[r];
    }
  }

  float lsum0[4] = {0.f, 0.f, 0.f, 0.f};
  float lsum1[4] = {0.f, 0.f, 0.f, 0.f};
  floatx4 o0[16] = {};
  floatx4 o1[16] = {};
  const float* cbb = colb + b*MPAD;

  __syncthreads();   // tile 0 staged (vmcnt drained by barrier semantics)

  for (int mt = 0; mt < NTIL; ++mt) {
    int cur = mt & 1;
    // issue stage of tile mt+1 into the other buffer (latency hides under compute)
    if (mt + 1 < NTIL) {
      const unsigned short* ks = kfb + (size_t)(mt+1)*16384;
      const unsigned short* vs = vfb + (size_t)(mt+1)*16384;
#pragma unroll
      for (int i = 0; i < 16; ++i) {
        int s = wave*16 + i;
        gl_lds16(ks + s*512 + lane*8, &kvK[cur^1][s*512]);
        gl_lds16(vs + s*512 + lane*8, &kvV[cur^1][s*512]);
      }
    }
    int m0 = mt*64;
    const unsigned short* kb = &kvK[cur][lane*8];
    const unsigned short* vb = &kvV[cur][lane*8];
    // ---- QK^T: each K fragment read once from LDS, feeds both row-groups
    floatx4 s0[4] = {}, s1[4] = {};
#pragma unroll
    for (int k = 0; k < 8; ++k)
#pragma unroll
      for (int t = 0; t < 4; ++t) {
        short8 kf = ld8(kb + (k*4 + t)*512);
        s0[t] = __builtin_amdgcn_mfma_f32_16x16x32_bf16(q0[k], kf, s0[t], 0, 0, 0);
        s1[t] = __builtin_amdgcn_mfma_f32_16x16x32_bf16(q1[k], kf, s1[t], 0, 0, 0);
      }
    // ---- fixed-max softmax: p = exp(s + colb[m] + rowb[r] - M_r)
    float cb[4];
#pragma unroll
    for (int t = 0; t < 4; ++t) cb[t] = cbb[m0 + t*16 + lo];
    // row-group 0
    short8 pf00, pf01, pf10, pf11;
    {
      float pr[4][4];
#pragma unroll
      for (int t = 0; t < 4; ++t)
#pragma unroll
        for (int r = 0; r < 4; ++r)
          pr[t][r] = s0[t][r] + cb[t] + crb0[r];
      if (mt == NTIL-1 && lo == 0) {
#pragma unroll
        for (int r = 0; r < 4; ++r) pr[0][r] = s0[0][r] - Msub0[r];
      }
#pragma unroll
      for (int t = 0; t < 4; ++t)
#pragma unroll
        for (int r = 0; r < 4; ++r) {
          float p = __expf(pr[t][r]);
          lsum0[r] += p;
          plw[(hi*4 + r)*72 + t*16 + lo] = f2b(p);
        }
      pf00 = *(const short8*)&plw[lo*72 + hi*8];
      pf01 = *(const short8*)&plw[lo*72 + 32 + hi*8];
    }
    // row-group 1
    {
      float pr[4][4];
#pragma unroll
      for (int t = 0; t < 4; ++t)
#pragma unroll
        for (int r = 0; r < 4; ++r)
          pr[t][r] = s1[t][r] + cb[t] + crb1[r];
      if (mt == NTIL-1 && lo == 0) {
#pragma unroll
        for (int r = 0; r < 4; ++r) pr[0][r] = s1[0][r] - Msub1[r];
      }
#pragma unroll
      for (int t = 0; t < 4; ++t)
#pragma unroll
        for (int r = 0; r < 4; ++r) {
          float p = __expf(pr[t][r]);
          lsum1[r] += p;
          plw[(hi*4 + r)*72 + t*16 + lo] = f2b(p);
        }
      pf10 = *(const short8*)&plw[lo*72 + hi*8];
      pf11 = *(const short8*)&plw[lo*72 + 32 + hi*8];
    }
    // ---- PV: each V fragment read once from LDS, feeds both row-groups
#pragma unroll
    for (int sl = 0; sl < 32; ++sl) {
      short8 vf = ld8(vb + sl*512);
      o0[sl & 15] = __builtin_amdgcn_mfma_f32_16x16x32_bf16((sl >> 4) ? pf01 : pf00,
                                                            vf, o0[sl & 15], 0, 0, 0);
      o1[sl & 15] = __builtin_amdgcn_mfma_f32_16x16x32_bf16((sl >> 4) ? pf11 : pf10,
                                                            vf, o1[sl & 15], 0, 0, 0);
    }
    __syncthreads();   // stage(mt+1) done + both waves finished reading buffers
  }

  // ---- l reductions over the 16 lo lanes
#pragma unroll
  for (int r = 0; r < 4; ++r) {
#pragma unroll
    for (int off = 1; off < 16; off <<= 1) {
      lsum0[r] += __shfl_xor(lsum0[r], off);
      lsum1[r] += __shfl_xor(lsum1[r], off);
    }
  }
  float inv0[4], inv1[4];
#pragma unroll
  for (int r = 0; r < 4; ++r) { inv0[r] = 1.0f / lsum0[r]; inv1[r] = 1.0f / lsum1[r]; }
  // ---- epilogue: per-wave chunked transpose (coalesced 64B store runs)
  const float* ib = img  + (size_t)b*CC*HWS;
  float*       ob = out0 + (size_t)b*CC*HWS;
#pragma unroll
  for (int c = 0; c < 4; ++c) {
#pragma unroll
    for (int tp = 0; tp < 4; ++tp) {
      int t = c*4 + tp;
#pragma unroll
      for (int r = 0; r < 4; ++r)
        plw[(hi*4 + r)*66 + tp*16 + lo] = f2b(o0[t][r]*inv0[r]);
    }
#pragma unroll
    for (int j = 0; j < 16; ++j) {
      int d = c*64 + hi*16 + j;
      float v = b2f(plw[lo*66 + hi*16 + j]);
      size_t idx = (size_t)d*HWS + n0 + lo;
      ob[idx] = v + ib[idx];
    }
  }
#pragma unroll
  for (int c = 0; c < 4; ++c) {
#pragma unroll
    for (int tp = 0; tp < 4; ++tp) {
      int t = c*4 + tp;
#pragma unroll
      for (int r = 0; r < 4; ++r)
        plw[(hi*4 + r)*66 + tp*16 + lo] = f2b(o1[t][r]*inv1[r]);
    }
#pragma unroll
    for (int j = 0; j < 16; ++j) {
      int d = c*64 + hi*16 + j;
      float v = b2f(plw[lo*66 + hi*16 + j]);
      size_t idx = (size_t)d*HWS + n0 + 16 + lo;
      ob[idx] = v + ib[idx];
    }
  }
}

// ---- queries[b][q][d] = sum_c img[b][c][id]*v_w[d][c]  (fp32 seq FMA)
__global__ __launch_bounds__(256) void gather_kernel(const float* __restrict__ img,
    const float* __restrict__ vw, const int* __restrict__ qids, float* __restrict__ out1) {
  int blk = blockIdx.x;
  int b = blk / 150, q = blk % 150;
  int dd = threadIdx.x;
  __shared__ float col[CC];
  int id = qids[b*150 + q];
  col[dd] = img[((size_t)b*CC + dd)*HWS + id];
  __syncthreads();
  const float* vr = vw + dd*CC;
  float acc = 0.f;
  for (int c = 0; c < CC; ++c) acc = fmaf(col[c], vr[c], acc);
  out1[((size_t)(b*150 + q))*CC + dd] = acc;
}

extern "C" void kernel_launch(void* const* d_in, const int* in_sizes, int n_in,
                              void* d_out, int out_size, void* d_ws, size_t ws_size,
                              hipStream_t stream) {
  const float* img  = (const float*)d_in[0];
  const float* exe  = (const float*)d_in[1];
  const float* mask = (const float*)d_in[2];
  const float* sim  = (const float*)d_in[3];
  const float* vw   = (const float*)d_in[4];
  float* out0 = (float*)d_out;
  float* out1 = out0 + (size_t)NB*CC*HWS;

  char* ws = (char*)d_ws;
  size_t o = 0;
  unsigned short* Kt  = (unsigned short*)(ws + o); o += (size_t)NB*MPAD*CC*2;
  unsigned short* Tb  = (unsigned short*)(ws + o); o += (size_t)NB*HWS*CC*2;
  unsigned short* Vbt = (unsigned short*)(ws + o); o += (size_t)NB*CC*MPAD*2;
  unsigned short* Kf  = (unsigned short*)(ws + o); o += (size_t)NB*NTIL*16384*2;
  unsigned short* Vf  = (unsigned short*)(ws + o); o += (size_t)NB*NTIL*16384*2;
  unsigned short* St  = (unsigned short*)(ws + o); o += (size_t)CC*CC*2;
  unsigned short* Vw  = (unsigned short*)(ws + o); o += (size_t)CC*CC*2;
  float*          scores = (float*)(ws + o);       o += (size_t)NB*HWS*4;
  float*          colb   = (float*)(ws + o);       o += (size_t)NB*MPAD*4;
  int*            qids   = (int*)(ws + o);         o += (size_t)NB*150*4;

  prep_mats  <<<dim3(CC),         dim3(CC),  0, stream>>>(sim, vw, St, Vw);
  colb_kernel<<<dim3(NB),         dim3(256), 0, stream>>>(mask, colb);
  build_kt   <<<dim3(NB, 65, 4),  dim3(256), 0, stream>>>(img, exe, Kt);
  gemm_small <<<dim3(NB, 64, 4),  dim3(256), 0, stream>>>(Kt, St, Tb, nullptr, 0);
  gemm_small <<<dim3(NB, 65, 4),  dim3(256), 0, stream>>>(Kt, Vw, nullptr, Vbt, 1);
  reorder_kv <<<dim3(NB, NTIL),   dim3(256), 0, stream>>>(Kt, Vbt, Kf, Vf);
  scores_kernel<<<dim3(NB, 256),  dim3(256), 0, stream>>>(img, sim, exe, scores);
  select_kernel<<<dim3(NB),       dim3(64),  0, stream>>>(scores, qids);
  flash_kernel <<<dim3(256),      dim3(128), 0, stream>>>(Tb, Kt, Kf, Vf, mask, colb, img, out0);
  gather_kernel<<<dim3(NB*150),   dim3(256), 0, stream>>>(img, vw, qids, out1);
}

// Round 3
// 447.317 us; speedup vs baseline: 1.1658x; 1.1658x over previous
//
#include <hip/hip_runtime.h>

#define CC   256
#define HWS  4096
#define MPAD 4160   // 65*64, rows >= 4097 zero-padded
#define NB   4
#define NTIL 65

typedef __attribute__((ext_vector_type(8))) short   short8;
typedef __attribute__((ext_vector_type(4))) float   floatx4;

static __device__ __forceinline__ short8 ld8(const unsigned short* p) {
  return *(const short8*)p;
}
static __device__ __forceinline__ void st8(unsigned short* p, short8 v) {
  *(short8*)p = v;
}
static __device__ __forceinline__ unsigned short f2b(float x) {
  union { float f; unsigned u; } v; v.f = x;
  unsigned r = v.u + 0x7FFFu + ((v.u >> 16) & 1u);
  return (unsigned short)(r >> 16);
}
static __device__ __forceinline__ float b2f(unsigned short x) {
  union { unsigned u; float f; } v; v.u = ((unsigned)x) << 16;
  return v.f;
}
// async global->LDS, 16B per lane, LDS dest = uniform base + lane*16
static __device__ __forceinline__ void gl_lds16(const unsigned short* g, unsigned short* l) {
  __builtin_amdgcn_global_load_lds(
      (const __attribute__((address_space(1))) unsigned int*)g,
      (__attribute__((address_space(3))) unsigned int*)l, 16, 0, 0);
}

// ---- St[d][c] = sim[c][d] (bf16), Vw[d][c] = v_w[d][c] (bf16)
__global__ void prep_mats(const float* __restrict__ sim, const float* __restrict__ vw,
                          unsigned short* __restrict__ St, unsigned short* __restrict__ Vw) {
  int dd = blockIdx.x, c = threadIdx.x;
  St[dd*CC + c] = f2b(sim[c*CC + dd]);
  Vw[dd*CC + c] = f2b(vw[dd*CC + c]);
}

// ---- colb[b][m]: additive column bias. m<HWS: (mask-1)*1e9; m==4096: 0; pad: -3e38
__global__ void colb_kernel(const float* __restrict__ mask, float* __restrict__ colb) {
  int b = blockIdx.x, tid = threadIdx.x;
  for (int m = tid; m < MPAD; m += 256) {
    float v;
    if (m < HWS)      v = (mask[b*HWS + m] - 1.0f) * 1e9f;
    else if (m == HWS) v = 0.0f;
    else               v = -3.0e38f;
    colb[b*MPAD + m] = v;
  }
}

// ---- Kt[b][m][d] = bf16(concat[b][d][m]); m==4096 -> 1.2*exe; m>4096 -> 0
__global__ void build_kt(const float* __restrict__ img, const float* __restrict__ exe,
                         unsigned short* __restrict__ Kt) {
  int b = blockIdx.x, mt = blockIdx.y, dt = blockIdx.z;
  int tid = threadIdx.x;
  int m0 = mt*64, d0 = dt*64;
  if (mt == 64) {
    for (int i = 0; i < 16; ++i) {
      int m = m0 + (tid>>6) + i*4;
      int d = d0 + (tid&63);
      unsigned short v = 0;
      if (m == 4096) v = f2b(1.2f * exe[b*CC + d]);
      Kt[((size_t)b*MPAD + m)*CC + d] = v;
    }
    return;
  }
  __shared__ float tile[64][65];
  for (int i = 0; i < 16; ++i) {
    int dl = (tid>>6) + i*4, ml = tid&63;
    tile[dl][ml] = img[((size_t)b*CC + d0+dl)*HWS + m0+ml];
  }
  __syncthreads();
  for (int i = 0; i < 16; ++i) {
    int ml = (tid>>6) + i*4, dl = tid&63;
    Kt[((size_t)b*MPAD + m0+ml)*CC + d0+dl] = f2b(tile[dl][ml]);
  }
}

// ---- mode 0: T[b][n][d] = bf16( sum_c Kt[n][c]*St[d][c] )           (rows < HWS)
// ---- mode 1: Vbt[b][d][m] = bf16( sum_c Kt[m][c]*Vw[d][c] )         (rows < MPAD)
__global__ __launch_bounds__(256) void gemm_small(const unsigned short* __restrict__ Kt,
    const unsigned short* __restrict__ Bm, unsigned short* __restrict__ Tout,
    unsigned short* __restrict__ Vbt, int mode) {
  int b  = blockIdx.x;
  int r0 = blockIdx.y*64 + (threadIdx.x>>6)*16;
  int c0 = blockIdx.z*64;
  int lane = threadIdx.x & 63;
  int lo = lane & 15, hi = lane >> 4;
  floatx4 acc[4] = {};
  const unsigned short* arow = Kt + ((size_t)b*MPAD + r0 + lo)*CC + hi*8;
#pragma unroll
  for (int k = 0; k < 8; ++k) {
    short8 af = ld8(arow + k*32);
#pragma unroll
    for (int t = 0; t < 4; ++t) {
      short8 bf = ld8(Bm + (size_t)(c0 + t*16 + lo)*CC + k*32 + hi*8);
      acc[t] = __builtin_amdgcn_mfma_f32_16x16x32_bf16(af, bf, acc[t], 0, 0, 0);
    }
  }
  if (mode == 0) {
#pragma unroll
    for (int t = 0; t < 4; ++t)
#pragma unroll
      for (int r = 0; r < 4; ++r) {
        int n = r0 + hi*4 + r, dd = c0 + t*16 + lo;
        Tout[((size_t)b*HWS + n)*CC + dd] = f2b(acc[t][r]);
      }
  } else {
#pragma unroll
    for (int t = 0; t < 4; ++t)
#pragma unroll
      for (int r = 0; r < 4; ++r) {
        int m = r0 + hi*4 + r, dd = c0 + t*16 + lo;
        Vbt[((size_t)b*CC + dd)*MPAD + m] = f2b(acc[t][r]);
      }
  }
}

// ---- reorder K and V into MFMA-fragment-major order, 1KB per instruction slot.
__global__ __launch_bounds__(256) void reorder_kv(const unsigned short* __restrict__ Kt,
    const unsigned short* __restrict__ Vbt, unsigned short* __restrict__ Kf,
    unsigned short* __restrict__ Vf) {
  int b = blockIdx.x, mt = blockIdx.y;
  int m0 = mt*64;
  int tid = threadIdx.x;
  int w = tid >> 6, lane = tid & 63;
  int lo = lane & 15, hi = lane >> 4;
  size_t tile = (size_t)(b*NTIL + mt)*16384;
  unsigned short* kf = Kf + tile;
  unsigned short* vf = Vf + tile;
  const unsigned short* ktb = Kt  + (size_t)b*MPAD*CC;
  const unsigned short* vtb = Vbt + (size_t)b*CC*MPAD;
#pragma unroll
  for (int i = 0; i < 8; ++i) {
    int s = i*4 + w;
    { // K slot
      int k = s >> 2, t = s & 3;
      short8 v = ld8(ktb + (size_t)(m0 + t*16 + lo)*CC + k*32 + hi*8);
      st8(kf + s*512 + lane*8, v);
    }
    { // V slot
      int h = s >> 4, t = s & 15;
      short8 v = ld8(vtb + (size_t)(t*16 + lo)*MPAD + m0 + h*32 + hi*8);
      st8(vf + s*512 + lane*8, v);
    }
  }
}

// ---- score mimicry of np/BLAS fp32 T-path, sequential FMA everywhere
__global__ __launch_bounds__(256) void scores_kernel(const float* __restrict__ img,
    const float* __restrict__ sim, const float* __restrict__ exe,
    float* __restrict__ score32) {
  int b = blockIdx.x, n0 = blockIdx.y*16;
  int d = threadIdx.x;
  __shared__ float U[16][257];        // U[nl][c] = img[b, c, n0+nl]
  __shared__ float R[16][256];        // T32[nl][d]
  __shared__ float E[256];
  for (int idx = threadIdx.x; idx < 16*256; idx += 256) {
    int nl = idx & 15, c = idx >> 4;
    U[nl][c] = img[((size_t)b*CC + c)*HWS + n0 + nl];
  }
  E[d] = 1.2f * exe[b*CC + d];
  __syncthreads();
  float acc[16];
#pragma unroll
  for (int nl = 0; nl < 16; ++nl) acc[nl] = 0.f;
  for (int c = 0; c < CC; ++c) {
    float s_cd = sim[c*CC + d];
#pragma unroll
    for (int nl = 0; nl < 16; ++nl) acc[nl] = fmaf(U[nl][c], s_cd, acc[nl]);
  }
#pragma unroll
  for (int nl = 0; nl < 16; ++nl) R[nl][d] = acc[nl];
  __syncthreads();
  if (d < 16) {
    float s = 0.f;
    for (int dd = 0; dd < CC; ++dd) s = fmaf(R[d][dd], E[dd], s);
    score32[b*HWS + n0 + d] = s;
  }
}

// ---- top-150 via exact radix-select on distinct 44-bit keys + bitonic-256 sort.
__global__ __launch_bounds__(64) void select_kernel(const float* __restrict__ scores,
                                                    int* __restrict__ qids) {
  int b = blockIdx.x, lane = threadIdx.x;
  __shared__ float sc[HWS];
  __shared__ unsigned long long kx[HWS];
  __shared__ unsigned long long list[256];
  __shared__ unsigned int hist[256];
  __shared__ unsigned int st[4];
  __shared__ unsigned long long sh_base;

  const floatx4* s4 = (const floatx4*)(scores + (size_t)b*HWS);
  floatx4* c4 = (floatx4*)sc;
#pragma unroll
  for (int i = 0; i < 16; ++i) c4[i*64 + lane] = s4[i*64 + lane];
  __syncthreads();

  for (int i = 0; i < 64; ++i) {
    int idx = i*64 + lane;
    int y = i, x = lane;
    float c0 = sc[idx];
    float v = c0;
    if (y >= 1 && y <= 62 && x >= 1 && x <= 62) {
      bool ismax = (c0 > sc[idx-64]) && (c0 >= sc[idx+64]) &&
                   (c0 > sc[idx-1])  && (c0 >= sc[idx+1]);
      if (!ismax) v = c0 - 1e9f;
    }
    unsigned u = __float_as_uint(v);
    u = (u & 0x80000000u) ? ~u : (u | 0x80000000u);
    kx[idx] = (((unsigned long long)u) << 12) | (unsigned long long)(4095 - idx);
  }
  __syncthreads();

  unsigned long long base = 0;
  unsigned int need = 150, C = 0;
  for (int s = 36; s >= 4; s -= 8) {
    for (int i = lane; i < 256; i += 64) hist[i] = 0;
    __syncthreads();
    unsigned long long pref = base >> (s + 8);
    for (int i = 0; i < 64; ++i) {
      unsigned long long k = kx[i*64 + lane];
      if ((k >> (s + 8)) == pref) atomicAdd(&hist[(unsigned)(k >> s) & 255u], 1u);
    }
    __syncthreads();
    if (lane == 0) {
      unsigned cum = 0; int B = 0;
      for (int bin = 255; bin >= 0; --bin) {
        cum += hist[bin];
        if (cum >= need) { B = bin; break; }
      }
      st[0] = (150u - need) + cum;
      st[1] = need - (cum - hist[B]);
      sh_base = base | ((unsigned long long)B << s);
    }
    __syncthreads();
    C = st[0]; need = st[1]; base = sh_base;
    if (C <= 256u) break;
  }

  if (lane == 0) st[2] = 0;
  __syncthreads();
  for (int i = 0; i < 64; ++i) {
    unsigned long long k = kx[i*64 + lane];
    if (k >= base) {
      unsigned p = atomicAdd(&st[2], 1u);
      list[p] = k;
    }
  }
  __syncthreads();
  for (int i = lane; i < 256; i += 64) if (i >= (int)C) list[i] = 0ull;
  __syncthreads();

  for (int kk = 2; kk <= 256; kk <<= 1) {
    for (int j = kk >> 1; j > 0; j >>= 1) {
#pragma unroll
      for (int tt = 0; tt < 2; ++tt) {
        int t = lane + tt*64;
        int i2 = ((t & ~(j - 1)) << 1) | (t & (j - 1));
        int p2 = i2 | j;
        bool desc = ((i2 & kk) == 0);
        unsigned long long a = list[i2], c = list[p2];
        bool sw = desc ? (a < c) : (a > c);
        if (sw) { list[i2] = c; list[p2] = a; }
      }
      __syncthreads();
    }
  }

  for (int q = lane; q < 150; q += 64)
    qids[b*150 + q] = 4095 - (int)(list[q] & 0xFFFull);
}

// ---- fused flash attention v7: v5's 4-wave/16-rows structure (proven 151us)
//      with K/V redirected through double-buffered LDS. v6 failed (266us)
//      because 128 threads left 2 SIMDs idle with zero TLP; v5 was L2-BW
//      bound (256KB/CU/tile = 4.7k cy). v7 keeps all 4 SIMDs + 4-wave TLP
//      and cuts per-CU L2 traffic 4x: each 64KB tile-pair staged ONCE per
//      block via global_load_lds (stage split across waves, one barrier per
//      tile - the m97 GEMM pattern), waves ds_read_b128 fragments from LDS.
//      New wall: LDS read port ~256KB/tile at ~130-250 B/cy -> ~1us/tile.
//      Arithmetic bit-identical to v5 (same MFMA order, same P path).
__global__ __launch_bounds__(256, 1) void flash_kernel(
    const unsigned short* __restrict__ Tb, const unsigned short* __restrict__ Kt,
    const unsigned short* __restrict__ Kf, const unsigned short* __restrict__ Vf,
    const float* __restrict__ mask, const float* __restrict__ colb,
    const float* __restrict__ img, float* __restrict__ out0) {
  int blk = blockIdx.x;                       // 256 blocks
  int b   = (blk & 7) >> 1;                   // batch pinned to XCD pair
  int g   = ((blk >> 3) << 1) | (blk & 1);    // n-group [0,64)
  int bn0 = g << 6;
  int tid = threadIdx.x;
  int wave = tid >> 6, lane = tid & 63;
  int lo = lane & 15, hi = lane >> 4;
  int n0 = bn0 + wave*16;                     // this wave's 16 Q-rows

  __shared__ unsigned short kvK[2][16384];    // 2 x 32KB K tiles (block-shared)
  __shared__ unsigned short kvV[2][16384];    // 2 x 32KB V tiles
  __shared__ unsigned short pbuf[4][1152];    // per-wave P / M-exchange / epilogue
  unsigned short* plw = &pbuf[wave][0];

  const unsigned short* kfb = Kf + (size_t)b*NTIL*16384;
  const unsigned short* vfb = Vf + (size_t)b*NTIL*16384;

  // stage tile 0 into buffer 0: wave w handles slots w*8 .. w*8+7 (K and V)
#pragma unroll
  for (int i = 0; i < 8; ++i) {
    int s = wave*8 + i;
    gl_lds16(kfb + s*512 + lane*8, &kvK[0][s*512]);
    gl_lds16(vfb + s*512 + lane*8, &kvV[0][s*512]);
  }

  // Q fragments for this wave's rows
  short8 q[8];
  const unsigned short* tb = Tb + ((size_t)b*HWS + n0 + lo)*CC + hi*8;
#pragma unroll
  for (int k = 0; k < 8; ++k) q[k] = ld8(tb + k*32);

  const float* mk = mask + b*HWS;

  // ---- prologue: diag and exe dots for this wave's 16 rows (fp32)
  float ddot = 0.f, edot = 0.f;
  {
    const unsigned short* kdp = Kt + ((size_t)b*MPAD + n0 + lo)*CC + hi*8;
    const unsigned short* kep = Kt + ((size_t)b*MPAD + HWS)*CC + hi*8;
#pragma unroll
    for (int k = 0; k < 8; ++k) {
      short8 kd = ld8(kdp + k*32);
      short8 ke = ld8(kep + k*32);
#pragma unroll
      for (int j = 0; j < 8; ++j) {
        float qf = b2f((unsigned short)q[k][j]);
        ddot = fmaf(qf, b2f((unsigned short)kd[j]), ddot);
        edot = fmaf(qf, b2f((unsigned short)ke[j]), edot);
      }
    }
    ddot += __shfl_xor(ddot, 16); ddot += __shfl_xor(ddot, 32);
    edot += __shfl_xor(edot, 16); edot += __shfl_xor(edot, 32);
  }
  float Mrow = ((mk[n0 + lo] == 1.0f) ? ddot : edot) + 2.0f;
  float* fM = (float*)plw;
  fM[lo] = Mrow;                   // intra-wave exchange (lockstep, lgkm-ordered)
  float crb[4], Msub[4];
#pragma unroll
  for (int r = 0; r < 4; ++r) {
    Msub[r] = fM[hi*4 + r];
    crb[r]  = (mk[n0 + hi*4 + r] - 1.0f)*1e9f - Msub[r];   // rowb - M
  }

  float lsum[4] = {0.f, 0.f, 0.f, 0.f};
  floatx4 o[16] = {};
  const float* cbb = colb + b*MPAD;

  __syncthreads();   // tile 0 staged (per-wave vmcnt drained before barrier)

  for (int mt = 0; mt < NTIL; ++mt) {
    int cur = mt & 1;
    // issue stage of tile mt+1 into the other buffer (hides under compute)
    if (mt + 1 < NTIL) {
      const unsigned short* ks = kfb + (size_t)(mt+1)*16384;
      const unsigned short* vs = vfb + (size_t)(mt+1)*16384;
#pragma unroll
      for (int i = 0; i < 8; ++i) {
        int s = wave*8 + i;
        gl_lds16(ks + s*512 + lane*8, &kvK[cur^1][s*512]);
        gl_lds16(vs + s*512 + lane*8, &kvV[cur^1][s*512]);
      }
    }
    int m0 = mt*64;
    // ---- QK^T: K fragments from LDS (each read shared by no one; port-parallel)
    floatx4 s[4] = {};
#pragma unroll
    for (int k = 0; k < 8; ++k)
#pragma unroll
      for (int t = 0; t < 4; ++t) {
        short8 kf = ld8(&kvK[cur][(k*4 + t)*512 + lane*8]);
        s[t] = __builtin_amdgcn_mfma_f32_16x16x32_bf16(q[k], kf, s[t], 0, 0, 0);
      }
    // ---- fixed-max softmax: p = exp(s + colb[m] + rowb[r] - M_r)
    float cb[4];
#pragma unroll
    for (int t = 0; t < 4; ++t) cb[t] = cbb[m0 + t*16 + lo];
    float pr[4][4];
#pragma unroll
    for (int t = 0; t < 4; ++t)
#pragma unroll
      for (int r = 0; r < 4; ++r)
        pr[t][r] = s[t][r] + cb[t] + crb[r];
    if (mt == NTIL-1 && lo == 0) {
      // exe column (m==4096, t==0): never row-masked -> drop rowb
#pragma unroll
      for (int r = 0; r < 4; ++r) pr[0][r] = s[0][r] - Msub[r];
    }
#pragma unroll
    for (int t = 0; t < 4; ++t)
#pragma unroll
      for (int r = 0; r < 4; ++r) {
        float p = __expf(pr[t][r]);
        lsum[r] += p;
        plw[(hi*4 + r)*72 + t*16 + lo] = f2b(p);
      }
    short8 pf0 = *(const short8*)&plw[lo*72 + hi*8];
    short8 pf1 = *(const short8*)&plw[lo*72 + 32 + hi*8];
    // ---- PV: V fragments from LDS
#pragma unroll
    for (int sl = 0; sl < 32; ++sl) {
      short8 vfr = ld8(&kvV[cur][sl*512 + lane*8]);
      o[sl & 15] = __builtin_amdgcn_mfma_f32_16x16x32_bf16((sl >> 4) ? pf1 : pf0,
                                                           vfr, o[sl & 15], 0, 0, 0);
    }
    __syncthreads();   // stage(mt+1) complete + all waves done reading cur
  }
  // ---- single end-of-kernel l reduction over the 16 lo lanes
#pragma unroll
  for (int r = 0; r < 4; ++r) {
#pragma unroll
    for (int off = 1; off < 16; off <<= 1) lsum[r] += __shfl_xor(lsum[r], off);
  }
  float inv[4];
#pragma unroll
  for (int r = 0; r < 4; ++r) inv[r] = 1.0f / lsum[r];
  // ---- epilogue: per-wave chunked transpose (coalesced 64B store runs)
  const float* ib = img  + (size_t)b*CC*HWS;
  float*       ob = out0 + (size_t)b*CC*HWS;
#pragma unroll
  for (int c = 0; c < 4; ++c) {
#pragma unroll
    for (int tp = 0; tp < 4; ++tp) {
      int t = c*4 + tp;
#pragma unroll
      for (int r = 0; r < 4; ++r)
        plw[(hi*4 + r)*66 + tp*16 + lo] = f2b(o[t][r]*inv[r]);
    }
#pragma unroll
    for (int j = 0; j < 16; ++j) {
      int d = c*64 + hi*16 + j;
      float v = b2f(plw[lo*66 + hi*16 + j]);
      size_t idx = (size_t)d*HWS + n0 + lo;
      ob[idx] = v + ib[idx];
    }
  }
}

// ---- queries[b][q][d] = sum_c img[b][c][id]*v_w[d][c]  (fp32 seq FMA)
__global__ __launch_bounds__(256) void gather_kernel(const float* __restrict__ img,
    const float* __restrict__ vw, const int* __restrict__ qids, float* __restrict__ out1) {
  int blk = blockIdx.x;
  int b = blk / 150, q = blk % 150;
  int dd = threadIdx.x;
  __shared__ float col[CC];
  int id = qids[b*150 + q];
  col[dd] = img[((size_t)b*CC + dd)*HWS + id];
  __syncthreads();
  const float* vr = vw + dd*CC;
  float acc = 0.f;
  for (int c = 0; c < CC; ++c) acc = fmaf(col[c], vr[c], acc);
  out1[((size_t)(b*150 + q))*CC + dd] = acc;
}

extern "C" void kernel_launch(void* const* d_in, const int* in_sizes, int n_in,
                              void* d_out, int out_size, void* d_ws, size_t ws_size,
                              hipStream_t stream) {
  const float* img  = (const float*)d_in[0];
  const float* exe  = (const float*)d_in[1];
  const float* mask = (const float*)d_in[2];
  const float* sim  = (const float*)d_in[3];
  const float* vw   = (const float*)d_in[4];
  float* out0 = (float*)d_out;
  float* out1 = out0 + (size_t)NB*CC*HWS;

  char* ws = (char*)d_ws;
  size_t o = 0;
  unsigned short* Kt  = (unsigned short*)(ws + o); o += (size_t)NB*MPAD*CC*2;
  unsigned short* Tb  = (unsigned short*)(ws + o); o += (size_t)NB*HWS*CC*2;
  unsigned short* Vbt = (unsigned short*)(ws + o); o += (size_t)NB*CC*MPAD*2;
  unsigned short* Kf  = (unsigned short*)(ws + o); o += (size_t)NB*NTIL*16384*2;
  unsigned short* Vf  = (unsigned short*)(ws + o); o += (size_t)NB*NTIL*16384*2;
  unsigned short* St  = (unsigned short*)(ws + o); o += (size_t)CC*CC*2;
  unsigned short* Vw  = (unsigned short*)(ws + o); o += (size_t)CC*CC*2;
  float*          scores = (float*)(ws + o);       o += (size_t)NB*HWS*4;
  float*          colb   = (float*)(ws + o);       o += (size_t)NB*MPAD*4;
  int*            qids   = (int*)(ws + o);         o += (size_t)NB*150*4;

  prep_mats  <<<dim3(CC),         dim3(CC),  0, stream>>>(sim, vw, St, Vw);
  colb_kernel<<<dim3(NB),         dim3(256), 0, stream>>>(mask, colb);
  build_kt   <<<dim3(NB, 65, 4),  dim3(256), 0, stream>>>(img, exe, Kt);
  gemm_small <<<dim3(NB, 64, 4),  dim3(256), 0, stream>>>(Kt, St, Tb, nullptr, 0);
  gemm_small <<<dim3(NB, 65, 4),  dim3(256), 0, stream>>>(Kt, Vw, nullptr, Vbt, 1);
  reorder_kv <<<dim3(NB, NTIL),   dim3(256), 0, stream>>>(Kt, Vbt, Kf, Vf);
  scores_kernel<<<dim3(NB, 256),  dim3(256), 0, stream>>>(img, sim, exe, scores);
  select_kernel<<<dim3(NB),       dim3(64),  0, stream>>>(scores, qids);
  flash_kernel <<<dim3(256),      dim3(256), 0, stream>>>(Tb, Kt, Kf, Vf, mask, colb, img, out0);
  gather_kernel<<<dim3(NB*150),   dim3(256), 0, stream>>>(img, vw, qids, out1);
}

// Round 4
// 414.572 us; speedup vs baseline: 1.2578x; 1.0790x over previous
//
#include <hip/hip_runtime.h>

#define CC   256
#define HWS  4096
#define MPAD 4160   // 65*64, rows >= 4097 zero-padded
#define NB   4
#define NTIL 65

typedef __attribute__((ext_vector_type(8))) short   short8;
typedef __attribute__((ext_vector_type(4))) float   floatx4;

static __device__ __forceinline__ short8 ld8(const unsigned short* p) {
  return *(const short8*)p;
}
static __device__ __forceinline__ void st8(unsigned short* p, short8 v) {
  *(short8*)p = v;
}
static __device__ __forceinline__ unsigned short f2b(float x) {
  union { float f; unsigned u; } v; v.f = x;
  unsigned r = v.u + 0x7FFFu + ((v.u >> 16) & 1u);
  return (unsigned short)(r >> 16);
}
static __device__ __forceinline__ float b2f(unsigned short x) {
  union { unsigned u; float f; } v; v.u = ((unsigned)x) << 16;
  return v.f;
}

// ---- St[d][c] = sim[c][d] (bf16), Vw[d][c] = v_w[d][c] (bf16)
__global__ void prep_mats(const float* __restrict__ sim, const float* __restrict__ vw,
                          unsigned short* __restrict__ St, unsigned short* __restrict__ Vw) {
  int dd = blockIdx.x, c = threadIdx.x;
  St[dd*CC + c] = f2b(sim[c*CC + dd]);
  Vw[dd*CC + c] = f2b(vw[dd*CC + c]);
}

// ---- colb[b][m]: additive column bias. m<HWS: (mask-1)*1e9; m==4096: 0; pad: -3e38
__global__ void colb_kernel(const float* __restrict__ mask, float* __restrict__ colb) {
  int b = blockIdx.x, tid = threadIdx.x;
  for (int m = tid; m < MPAD; m += 256) {
    float v;
    if (m < HWS)      v = (mask[b*HWS + m] - 1.0f) * 1e9f;
    else if (m == HWS) v = 0.0f;
    else               v = -3.0e38f;
    colb[b*MPAD + m] = v;
  }
}

// ---- Kt[b][m][d] = bf16(concat[b][d][m]); m==4096 -> 1.2*exe; m>4096 -> 0
__global__ void build_kt(const float* __restrict__ img, const float* __restrict__ exe,
                         unsigned short* __restrict__ Kt) {
  int b = blockIdx.x, mt = blockIdx.y, dt = blockIdx.z;
  int tid = threadIdx.x;
  int m0 = mt*64, d0 = dt*64;
  if (mt == 64) {
    for (int i = 0; i < 16; ++i) {
      int m = m0 + (tid>>6) + i*4;
      int d = d0 + (tid&63);
      unsigned short v = 0;
      if (m == 4096) v = f2b(1.2f * exe[b*CC + d]);
      Kt[((size_t)b*MPAD + m)*CC + d] = v;
    }
    return;
  }
  __shared__ float tile[64][65];
  for (int i = 0; i < 16; ++i) {
    int dl = (tid>>6) + i*4, ml = tid&63;
    tile[dl][ml] = img[((size_t)b*CC + d0+dl)*HWS + m0+ml];
  }
  __syncthreads();
  for (int i = 0; i < 16; ++i) {
    int ml = (tid>>6) + i*4, dl = tid&63;
    Kt[((size_t)b*MPAD + m0+ml)*CC + d0+dl] = f2b(tile[dl][ml]);
  }
}

// ---- mode 0: T[b][n][d] = bf16( sum_c Kt[n][c]*St[d][c] )           (rows < HWS)
// ---- mode 1: Vbt[b][d][m] = bf16( sum_c Kt[m][c]*Vw[d][c] )         (rows < MPAD)
__global__ __launch_bounds__(256) void gemm_small(const unsigned short* __restrict__ Kt,
    const unsigned short* __restrict__ Bm, unsigned short* __restrict__ Tout,
    unsigned short* __restrict__ Vbt, int mode) {
  int b  = blockIdx.x;
  int r0 = blockIdx.y*64 + (threadIdx.x>>6)*16;
  int c0 = blockIdx.z*64;
  int lane = threadIdx.x & 63;
  int lo = lane & 15, hi = lane >> 4;
  floatx4 acc[4] = {};
  const unsigned short* arow = Kt + ((size_t)b*MPAD + r0 + lo)*CC + hi*8;
#pragma unroll
  for (int k = 0; k < 8; ++k) {
    short8 af = ld8(arow + k*32);
#pragma unroll
    for (int t = 0; t < 4; ++t) {
      short8 bf = ld8(Bm + (size_t)(c0 + t*16 + lo)*CC + k*32 + hi*8);
      acc[t] = __builtin_amdgcn_mfma_f32_16x16x32_bf16(af, bf, acc[t], 0, 0, 0);
    }
  }
  if (mode == 0) {
#pragma unroll
    for (int t = 0; t < 4; ++t)
#pragma unroll
      for (int r = 0; r < 4; ++r) {
        int n = r0 + hi*4 + r, dd = c0 + t*16 + lo;
        Tout[((size_t)b*HWS + n)*CC + dd] = f2b(acc[t][r]);
      }
  } else {
#pragma unroll
    for (int t = 0; t < 4; ++t)
#pragma unroll
      for (int r = 0; r < 4; ++r) {
        int m = r0 + hi*4 + r, dd = c0 + t*16 + lo;
        Vbt[((size_t)b*CC + dd)*MPAD + m] = f2b(acc[t][r]);
      }
  }
}

// ---- reorder K and V into MFMA-fragment-major order, 1KB per instruction slot.
__global__ __launch_bounds__(256) void reorder_kv(const unsigned short* __restrict__ Kt,
    const unsigned short* __restrict__ Vbt, unsigned short* __restrict__ Kf,
    unsigned short* __restrict__ Vf) {
  int b = blockIdx.x, mt = blockIdx.y;
  int m0 = mt*64;
  int tid = threadIdx.x;
  int w = tid >> 6, lane = tid & 63;
  int lo = lane & 15, hi = lane >> 4;
  size_t tile = (size_t)(b*NTIL + mt)*16384;
  unsigned short* kf = Kf + tile;
  unsigned short* vf = Vf + tile;
  const unsigned short* ktb = Kt  + (size_t)b*MPAD*CC;
  const unsigned short* vtb = Vbt + (size_t)b*CC*MPAD;
#pragma unroll
  for (int i = 0; i < 8; ++i) {
    int s = i*4 + w;
    { // K slot
      int k = s >> 2, t = s & 3;
      short8 v = ld8(ktb + (size_t)(m0 + t*16 + lo)*CC + k*32 + hi*8);
      st8(kf + s*512 + lane*8, v);
    }
    { // V slot
      int h = s >> 4, t = s & 15;
      short8 v = ld8(vtb + (size_t)(t*16 + lo)*MPAD + m0 + h*32 + hi*8);
      st8(vf + s*512 + lane*8, v);
    }
  }
}

// ---- score mimicry of np/BLAS fp32 T-path, sequential FMA everywhere
__global__ __launch_bounds__(256) void scores_kernel(const float* __restrict__ img,
    const float* __restrict__ sim, const float* __restrict__ exe,
    float* __restrict__ score32) {
  int b = blockIdx.x, n0 = blockIdx.y*16;
  int d = threadIdx.x;
  __shared__ float U[16][257];        // U[nl][c] = img[b, c, n0+nl]
  __shared__ float R[16][256];        // T32[nl][d]
  __shared__ float E[256];
  for (int idx = threadIdx.x; idx < 16*256; idx += 256) {
    int nl = idx & 15, c = idx >> 4;
    U[nl][c] = img[((size_t)b*CC + c)*HWS + n0 + nl];
  }
  E[d] = 1.2f * exe[b*CC + d];
  __syncthreads();
  float acc[16];
#pragma unroll
  for (int nl = 0; nl < 16; ++nl) acc[nl] = 0.f;
  for (int c = 0; c < CC; ++c) {
    float s_cd = sim[c*CC + d];
#pragma unroll
    for (int nl = 0; nl < 16; ++nl) acc[nl] = fmaf(U[nl][c], s_cd, acc[nl]);
  }
#pragma unroll
  for (int nl = 0; nl < 16; ++nl) R[nl][d] = acc[nl];
  __syncthreads();
  if (d < 16) {
    float s = 0.f;
    for (int dd = 0; dd < CC; ++dd) s = fmaf(R[d][dd], E[dd], s);
    score32[b*HWS + n0 + d] = s;
  }
}

// ---- top-150 via exact radix-select on distinct 44-bit keys + bitonic-256 sort.
__global__ __launch_bounds__(64) void select_kernel(const float* __restrict__ scores,
                                                    int* __restrict__ qids) {
  int b = blockIdx.x, lane = threadIdx.x;
  __shared__ float sc[HWS];
  __shared__ unsigned long long kx[HWS];
  __shared__ unsigned long long list[256];
  __shared__ unsigned int hist[256];
  __shared__ unsigned int st[4];
  __shared__ unsigned long long sh_base;

  const floatx4* s4 = (const floatx4*)(scores + (size_t)b*HWS);
  floatx4* c4 = (floatx4*)sc;
#pragma unroll
  for (int i = 0; i < 16; ++i) c4[i*64 + lane] = s4[i*64 + lane];
  __syncthreads();

  for (int i = 0; i < 64; ++i) {
    int idx = i*64 + lane;
    int y = i, x = lane;
    float c0 = sc[idx];
    float v = c0;
    if (y >= 1 && y <= 62 && x >= 1 && x <= 62) {
      bool ismax = (c0 > sc[idx-64]) && (c0 >= sc[idx+64]) &&
                   (c0 > sc[idx-1])  && (c0 >= sc[idx+1]);
      if (!ismax) v = c0 - 1e9f;
    }
    unsigned u = __float_as_uint(v);
    u = (u & 0x80000000u) ? ~u : (u | 0x80000000u);
    kx[idx] = (((unsigned long long)u) << 12) | (unsigned long long)(4095 - idx);
  }
  __syncthreads();

  unsigned long long base = 0;
  unsigned int need = 150, C = 0;
  for (int s = 36; s >= 4; s -= 8) {
    for (int i = lane; i < 256; i += 64) hist[i] = 0;
    __syncthreads();
    unsigned long long pref = base >> (s + 8);
    for (int i = 0; i < 64; ++i) {
      unsigned long long k = kx[i*64 + lane];
      if ((k >> (s + 8)) == pref) atomicAdd(&hist[(unsigned)(k >> s) & 255u], 1u);
    }
    __syncthreads();
    if (lane == 0) {
      unsigned cum = 0; int B = 0;
      for (int bin = 255; bin >= 0; --bin) {
        cum += hist[bin];
        if (cum >= need) { B = bin; break; }
      }
      st[0] = (150u - need) + cum;
      st[1] = need - (cum - hist[B]);
      sh_base = base | ((unsigned long long)B << s);
    }
    __syncthreads();
    C = st[0]; need = st[1]; base = sh_base;
    if (C <= 256u) break;
  }

  if (lane == 0) st[2] = 0;
  __syncthreads();
  for (int i = 0; i < 64; ++i) {
    unsigned long long k = kx[i*64 + lane];
    if (k >= base) {
      unsigned p = atomicAdd(&st[2], 1u);
      list[p] = k;
    }
  }
  __syncthreads();
  for (int i = lane; i < 256; i += 64) if (i >= (int)C) list[i] = 0ull;
  __syncthreads();

  for (int kk = 2; kk <= 256; kk <<= 1) {
    for (int j = kk >> 1; j > 0; j >>= 1) {
#pragma unroll
      for (int tt = 0; tt < 2; ++tt) {
        int t = lane + tt*64;
        int i2 = ((t & ~(j - 1)) << 1) | (t & (j - 1));
        int p2 = i2 | j;
        bool desc = ((i2 & kk) == 0);
        unsigned long long a = list[i2], c = list[p2];
        bool sw = desc ? (a < c) : (a > c);
        if (sw) { list[i2] = c; list[p2] = a; }
      }
      __syncthreads();
    }
  }

  for (int q = lane; q < 150; q += 64)
    qids[b*150 + q] = 4095 - (int)(list[q] & 0xFFFull);
}

// ---- fused flash attention v8: v5's register-streaming structure (proven the
//      best stall profile: loads a tile ahead, no barriers, independent waves)
//      + dual 16-row groups per wave (v6-verified arithmetic: each K/V register
//      read feeds TWO row-groups -> bytes/row halved) + KV-range SPLIT in two
//      halves so the grid stays 256 blocks x 4 waves (full chip, 4 SIMDs/CU).
//      Fixed-max softmax makes halves exactly combinable: M is analytic per
//      row, so partial sums (o, l) just add. Each half scatters fp32 partials
//      (half0 -> out0, half1 -> accH) + per-row l; finalize_kernel does
//      (p0+p1)*inv -> bf16 round (v5's single rounding) -> +img.
//      Per-CU L2 traffic: 16.6MB (v5) -> 8.3MB -> BW floor ~62us.
__global__ __launch_bounds__(256, 1) void flash_kernel(
    const unsigned short* __restrict__ Tb, const unsigned short* __restrict__ Kt,
    const unsigned short* __restrict__ Kf, const unsigned short* __restrict__ Vf,
    const float* __restrict__ mask, const float* __restrict__ colb,
    float* __restrict__ acc0, float* __restrict__ accH, float* __restrict__ lsums) {
  int blk = blockIdx.x;                       // 256 blocks
  int b    = (blk & 7) >> 1;                  // batch pinned to XCD pair
  int half = blk & 1;                         // KV half pinned to XCD
  int g    = blk >> 3;                        // row-group-128 [0,32)
  int tid = threadIdx.x;
  int wave = tid >> 6, lane = tid & 63;
  int lo = lane & 15, hi = lane >> 4;
  int n0 = g*128 + wave*32;                   // this wave's 32 Q-rows
  int t0 = half ? 33 : 0, t1 = half ? NTIL : 33;

  __shared__ unsigned short pbuf[4][1152];    // per-wave P / M-exchange
  unsigned short* plw = &pbuf[wave][0];

  // Q fragments for this wave's two row-groups
  short8 q0[8], q1[8];
  const unsigned short* tb0 = Tb + ((size_t)b*HWS + n0 + lo)*CC + hi*8;
#pragma unroll
  for (int k = 0; k < 8; ++k) { q0[k] = ld8(tb0 + k*32); q1[k] = ld8(tb0 + 16*CC + k*32); }

  const float* mk = mask + b*HWS;

  // ---- prologue: diag and exe dots (fp32), fixed row max M = pick + 2
  float crb0[4], Msub0[4], crb1[4], Msub1[4];
  {
    const unsigned short* kep = Kt + ((size_t)b*MPAD + HWS)*CC + hi*8;
    // row-group 0
    float ddot = 0.f, edot = 0.f;
    const unsigned short* kdp = Kt + ((size_t)b*MPAD + n0 + lo)*CC + hi*8;
#pragma unroll
    for (int k = 0; k < 8; ++k) {
      short8 kd = ld8(kdp + k*32);
      short8 ke = ld8(kep + k*32);
#pragma unroll
      for (int j = 0; j < 8; ++j) {
        float qf = b2f((unsigned short)q0[k][j]);
        ddot = fmaf(qf, b2f((unsigned short)kd[j]), ddot);
        edot = fmaf(qf, b2f((unsigned short)ke[j]), edot);
      }
    }
    ddot += __shfl_xor(ddot, 16); ddot += __shfl_xor(ddot, 32);
    edot += __shfl_xor(edot, 16); edot += __shfl_xor(edot, 32);
    float Mrow = ((mk[n0 + lo] == 1.0f) ? ddot : edot) + 2.0f;
    float* fM = (float*)plw;
    fM[lo] = Mrow;
#pragma unroll
    for (int r = 0; r < 4; ++r) {
      Msub0[r] = fM[hi*4 + r];
      crb0[r]  = (mk[n0 + hi*4 + r] - 1.0f)*1e9f - Msub0[r];
    }
    // row-group 1
    ddot = 0.f; edot = 0.f;
    const unsigned short* kdp1 = Kt + ((size_t)b*MPAD + n0 + 16 + lo)*CC + hi*8;
#pragma unroll
    for (int k = 0; k < 8; ++k) {
      short8 kd = ld8(kdp1 + k*32);
      short8 ke = ld8(kep + k*32);
#pragma unroll
      for (int j = 0; j < 8; ++j) {
        float qf = b2f((unsigned short)q1[k][j]);
        ddot = fmaf(qf, b2f((unsigned short)kd[j]), ddot);
        edot = fmaf(qf, b2f((unsigned short)ke[j]), edot);
      }
    }
    ddot += __shfl_xor(ddot, 16); ddot += __shfl_xor(ddot, 32);
    edot += __shfl_xor(edot, 16); edot += __shfl_xor(edot, 32);
    float Mrow1 = ((mk[n0 + 16 + lo] == 1.0f) ? ddot : edot) + 2.0f;
    fM[lo] = Mrow1;
#pragma unroll
    for (int r = 0; r < 4; ++r) {
      Msub1[r] = fM[hi*4 + r];
      crb1[r]  = (mk[n0 + 16 + hi*4 + r] - 1.0f)*1e9f - Msub1[r];
    }
  }

  float lsum0[4] = {0.f, 0.f, 0.f, 0.f};
  float lsum1[4] = {0.f, 0.f, 0.f, 0.f};
  floatx4 o0[16] = {};
  floatx4 o1[16] = {};
  const float* cbb = colb + b*MPAD;

  const unsigned short* kfb = Kf + (size_t)b*NTIL*16384 + lane*8;
  const unsigned short* vfb = Vf + (size_t)b*NTIL*16384 + lane*8;

  // preload K tile t0 into registers (32 x short8)
  short8 ka[32], vaA[16], vaB[16];
#pragma unroll
  for (int s2 = 0; s2 < 32; ++s2) ka[s2] = ld8(kfb + (size_t)t0*16384 + s2*512);

  for (int mt = t0; mt < t1; ++mt) {
    int m0 = mt*64;
    const unsigned short* vs = vfb + (size_t)mt*16384;
    // issue V(mt) first half; consumed by PV-A after QK+softmax
#pragma unroll
    for (int s2 = 0; s2 < 16; ++s2) vaA[s2] = ld8(vs + s2*512);
    // ---- QK^T dual: each K fragment feeds both row-groups
    floatx4 s0[4] = {}, s1[4] = {};
#pragma unroll
    for (int k = 0; k < 8; ++k)
#pragma unroll
      for (int t = 0; t < 4; ++t) {
        s0[t] = __builtin_amdgcn_mfma_f32_16x16x32_bf16(q0[k], ka[k*4 + t], s0[t], 0, 0, 0);
        s1[t] = __builtin_amdgcn_mfma_f32_16x16x32_bf16(q1[k], ka[k*4 + t], s1[t], 0, 0, 0);
      }
    // issue V(mt) second half, then K(mt+1) (ka dead now)
#pragma unroll
    for (int s2 = 0; s2 < 16; ++s2) vaB[s2] = ld8(vs + (16 + s2)*512);
    if (mt + 1 < t1) {
      const unsigned short* ks = kfb + (size_t)(mt+1)*16384;
#pragma unroll
      for (int s2 = 0; s2 < 32; ++s2) ka[s2] = ld8(ks + s2*512);
    }
    // ---- fixed-max softmax: p = exp(s + colb[m] + rowb[r] - M_r)
    float cb[4];
#pragma unroll
    for (int t = 0; t < 4; ++t) cb[t] = cbb[m0 + t*16 + lo];
    short8 pf00, pf01, pf10, pf11;
    { // row-group 0
      float pr[4][4];
#pragma unroll
      for (int t = 0; t < 4; ++t)
#pragma unroll
        for (int r = 0; r < 4; ++r)
          pr[t][r] = s0[t][r] + cb[t] + crb0[r];
      if (mt == NTIL-1 && lo == 0) {
        // exe column (m==4096, t==0): never row-masked -> drop rowb
#pragma unroll
        for (int r = 0; r < 4; ++r) pr[0][r] = s0[0][r] - Msub0[r];
      }
#pragma unroll
      for (int t = 0; t < 4; ++t)
#pragma unroll
        for (int r = 0; r < 4; ++r) {
          float p = __expf(pr[t][r]);
          lsum0[r] += p;
          plw[(hi*4 + r)*72 + t*16 + lo] = f2b(p);
        }
      pf00 = *(const short8*)&plw[lo*72 + hi*8];
      pf01 = *(const short8*)&plw[lo*72 + 32 + hi*8];
    }
    { // row-group 1
      float pr[4][4];
#pragma unroll
      for (int t = 0; t < 4; ++t)
#pragma unroll
        for (int r = 0; r < 4; ++r)
          pr[t][r] = s1[t][r] + cb[t] + crb1[r];
      if (mt == NTIL-1 && lo == 0) {
#pragma unroll
        for (int r = 0; r < 4; ++r) pr[0][r] = s1[0][r] - Msub1[r];
      }
#pragma unroll
      for (int t = 0; t < 4; ++t)
#pragma unroll
        for (int r = 0; r < 4; ++r) {
          float p = __expf(pr[t][r]);
          lsum1[r] += p;
          plw[(hi*4 + r)*72 + t*16 + lo] = f2b(p);
        }
      pf10 = *(const short8*)&plw[lo*72 + hi*8];
      pf11 = *(const short8*)&plw[lo*72 + 32 + hi*8];
    }
    // ---- PV dual: each V fragment feeds both row-groups
#pragma unroll
    for (int sl = 0; sl < 16; ++sl) {
      o0[sl] = __builtin_amdgcn_mfma_f32_16x16x32_bf16(pf00, vaA[sl], o0[sl], 0, 0, 0);
      o1[sl] = __builtin_amdgcn_mfma_f32_16x16x32_bf16(pf10, vaA[sl], o1[sl], 0, 0, 0);
    }
#pragma unroll
    for (int sl = 0; sl < 16; ++sl) {
      o0[sl] = __builtin_amdgcn_mfma_f32_16x16x32_bf16(pf01, vaB[sl], o0[sl], 0, 0, 0);
      o1[sl] = __builtin_amdgcn_mfma_f32_16x16x32_bf16(pf11, vaB[sl], o1[sl], 0, 0, 0);
    }
  }
  // ---- l reduction over the 16 lo lanes (both groups)
#pragma unroll
  for (int r = 0; r < 4; ++r) {
#pragma unroll
    for (int off = 1; off < 16; off <<= 1) {
      lsum0[r] += __shfl_xor(lsum0[r], off);
      lsum1[r] += __shfl_xor(lsum1[r], off);
    }
  }
  // ---- epilogue: scatter fp32 UNNORMALIZED partials (no rounding here)
  float* op = (half ? accH : acc0) + (size_t)b*CC*HWS;
#pragma unroll
  for (int t = 0; t < 16; ++t)
#pragma unroll
    for (int r = 0; r < 4; ++r) {
      op[(size_t)(t*16 + lo)*HWS + n0 + hi*4 + r]      = o0[t][r];
      op[(size_t)(t*16 + lo)*HWS + n0 + 16 + hi*4 + r] = o1[t][r];
    }
  if (lo == 0) {
    float* lp = lsums + ((size_t)(half*NB + b))*HWS;
#pragma unroll
    for (int r = 0; r < 4; ++r) {
      lp[n0 + hi*4 + r]      = lsum0[r];
      lp[n0 + 16 + hi*4 + r] = lsum1[r];
    }
  }
}

// ---- out0[b][d][n] = bf16_round( (p0+p1) * 1/(l0+l1) ) + img  (coalesced)
__global__ __launch_bounds__(256) void finalize_kernel(const float* __restrict__ accH,
    const float* __restrict__ lsums, const float* __restrict__ img,
    float* __restrict__ out0) {
  int b = blockIdx.x >> 8;
  int d = blockIdx.x & 255;
  size_t base = ((size_t)b*CC + d)*HWS;
  const float* l0 = lsums + (size_t)b*HWS;
  const float* l1 = lsums + (size_t)(NB + b)*HWS;
  for (int n = threadIdx.x; n < HWS; n += 256) {
    float inv = 1.0f / (l0[n] + l1[n]);
    float o = (out0[base + n] + accH[base + n]) * inv;
    out0[base + n] = b2f(f2b(o)) + img[base + n];
  }
}

// ---- queries[b][q][d] = sum_c img[b][c][id]*v_w[d][c]  (fp32 seq FMA)
__global__ __launch_bounds__(256) void gather_kernel(const float* __restrict__ img,
    const float* __restrict__ vw, const int* __restrict__ qids, float* __restrict__ out1) {
  int blk = blockIdx.x;
  int b = blk / 150, q = blk % 150;
  int dd = threadIdx.x;
  __shared__ float col[CC];
  int id = qids[b*150 + q];
  col[dd] = img[((size_t)b*CC + dd)*HWS + id];
  __syncthreads();
  const float* vr = vw + dd*CC;
  float acc = 0.f;
  for (int c = 0; c < CC; ++c) acc = fmaf(col[c], vr[c], acc);
  out1[((size_t)(b*150 + q))*CC + dd] = acc;
}

extern "C" void kernel_launch(void* const* d_in, const int* in_sizes, int n_in,
                              void* d_out, int out_size, void* d_ws, size_t ws_size,
                              hipStream_t stream) {
  const float* img  = (const float*)d_in[0];
  const float* exe  = (const float*)d_in[1];
  const float* mask = (const float*)d_in[2];
  const float* sim  = (const float*)d_in[3];
  const float* vw   = (const float*)d_in[4];
  float* out0 = (float*)d_out;
  float* out1 = out0 + (size_t)NB*CC*HWS;

  char* ws = (char*)d_ws;
  size_t o = 0;
  unsigned short* Kt  = (unsigned short*)(ws + o); o += (size_t)NB*MPAD*CC*2;
  unsigned short* Tb  = (unsigned short*)(ws + o); o += (size_t)NB*HWS*CC*2;
  unsigned short* Vbt = (unsigned short*)(ws + o); o += (size_t)NB*CC*MPAD*2;
  unsigned short* Kf  = (unsigned short*)(ws + o); o += (size_t)NB*NTIL*16384*2;
  unsigned short* Vf  = (unsigned short*)(ws + o); o += (size_t)NB*NTIL*16384*2;
  unsigned short* St  = (unsigned short*)(ws + o); o += (size_t)CC*CC*2;
  unsigned short* Vw  = (unsigned short*)(ws + o); o += (size_t)CC*CC*2;
  float*          scores = (float*)(ws + o);       o += (size_t)NB*HWS*4;
  float*          colb   = (float*)(ws + o);       o += (size_t)NB*MPAD*4;
  int*            qids   = (int*)(ws + o);         o += (size_t)NB*150*4;
  float*          accH   = (float*)(ws + o);       o += (size_t)NB*CC*HWS*4;
  float*          lsums  = (float*)(ws + o);       o += (size_t)2*NB*HWS*4;

  prep_mats  <<<dim3(CC),         dim3(CC),  0, stream>>>(sim, vw, St, Vw);
  colb_kernel<<<dim3(NB),         dim3(256), 0, stream>>>(mask, colb);
  build_kt   <<<dim3(NB, 65, 4),  dim3(256), 0, stream>>>(img, exe, Kt);
  gemm_small <<<dim3(NB, 64, 4),  dim3(256), 0, stream>>>(Kt, St, Tb, nullptr, 0);
  gemm_small <<<dim3(NB, 65, 4),  dim3(256), 0, stream>>>(Kt, Vw, nullptr, Vbt, 1);
  reorder_kv <<<dim3(NB, NTIL),   dim3(256), 0, stream>>>(Kt, Vbt, Kf, Vf);
  scores_kernel<<<dim3(NB, 256),  dim3(256), 0, stream>>>(img, sim, exe, scores);
  select_kernel<<<dim3(NB),       dim3(64),  0, stream>>>(scores, qids);
  flash_kernel <<<dim3(256),      dim3(256), 0, stream>>>(Tb, Kt, Kf, Vf, mask, colb,
                                                          out0, accH, lsums);
  finalize_kernel<<<dim3(NB*CC),  dim3(256), 0, stream>>>(accH, lsums, img, out0);
  gather_kernel<<<dim3(NB*150),   dim3(256), 0, stream>>>(img, vw, qids, out1);
}

// Round 5
// 385.726 us; speedup vs baseline: 1.3519x; 1.0748x over previous
//
#include <hip/hip_runtime.h>

#define CC   256
#define HWS  4096
#define MPAD 4160   // 65*64, rows >= 4097 zero-padded
#define NB   4
#define NTIL 65

typedef __attribute__((ext_vector_type(8))) short   short8;
typedef __attribute__((ext_vector_type(4))) float   floatx4;

static __device__ __forceinline__ short8 ld8(const unsigned short* p) {
  return *(const short8*)p;
}
static __device__ __forceinline__ void st8(unsigned short* p, short8 v) {
  *(short8*)p = v;
}
static __device__ __forceinline__ unsigned short f2b(float x) {
  union { float f; unsigned u; } v; v.f = x;
  unsigned r = v.u + 0x7FFFu + ((v.u >> 16) & 1u);
  return (unsigned short)(r >> 16);
}
static __device__ __forceinline__ float b2f(unsigned short x) {
  union { unsigned u; float f; } v; v.u = ((unsigned)x) << 16;
  return v.f;
}

// ---- St[d][c] = sim[c][d] (bf16), Vw[d][c] = v_w[d][c] (bf16)
__global__ void prep_mats(const float* __restrict__ sim, const float* __restrict__ vw,
                          unsigned short* __restrict__ St, unsigned short* __restrict__ Vw) {
  int dd = blockIdx.x, c = threadIdx.x;
  St[dd*CC + c] = f2b(sim[c*CC + dd]);
  Vw[dd*CC + c] = f2b(vw[dd*CC + c]);
}

// ---- colb[b][m]: additive column bias. m<HWS: (mask-1)*1e9; m==4096: 0; pad: -3e38
__global__ void colb_kernel(const float* __restrict__ mask, float* __restrict__ colb) {
  int b = blockIdx.x, tid = threadIdx.x;
  for (int m = tid; m < MPAD; m += 256) {
    float v;
    if (m < HWS)      v = (mask[b*HWS + m] - 1.0f) * 1e9f;
    else if (m == HWS) v = 0.0f;
    else               v = -3.0e38f;
    colb[b*MPAD + m] = v;
  }
}

// ---- Kt[b][m][d] = bf16(concat[b][d][m]); m==4096 -> 1.2*exe; m>4096 -> 0
__global__ void build_kt(const float* __restrict__ img, const float* __restrict__ exe,
                         unsigned short* __restrict__ Kt) {
  int b = blockIdx.x, mt = blockIdx.y, dt = blockIdx.z;
  int tid = threadIdx.x;
  int m0 = mt*64, d0 = dt*64;
  if (mt == 64) {
    for (int i = 0; i < 16; ++i) {
      int m = m0 + (tid>>6) + i*4;
      int d = d0 + (tid&63);
      unsigned short v = 0;
      if (m == 4096) v = f2b(1.2f * exe[b*CC + d]);
      Kt[((size_t)b*MPAD + m)*CC + d] = v;
    }
    return;
  }
  __shared__ float tile[64][65];
  for (int i = 0; i < 16; ++i) {
    int dl = (tid>>6) + i*4, ml = tid&63;
    tile[dl][ml] = img[((size_t)b*CC + d0+dl)*HWS + m0+ml];
  }
  __syncthreads();
  for (int i = 0; i < 16; ++i) {
    int ml = (tid>>6) + i*4, dl = tid&63;
    Kt[((size_t)b*MPAD + m0+ml)*CC + d0+dl] = f2b(tile[dl][ml]);
  }
}

// ---- mode 0: T[b][n][d] = bf16( sum_c Kt[n][c]*St[d][c] )           (rows < HWS)
// ---- mode 1: Vbt[b][d][m] = bf16( sum_c Kt[m][c]*Vw[d][c] )         (rows < MPAD)
__global__ __launch_bounds__(256) void gemm_small(const unsigned short* __restrict__ Kt,
    const unsigned short* __restrict__ Bm, unsigned short* __restrict__ Tout,
    unsigned short* __restrict__ Vbt, int mode) {
  int b  = blockIdx.x;
  int r0 = blockIdx.y*64 + (threadIdx.x>>6)*16;
  int c0 = blockIdx.z*64;
  int lane = threadIdx.x & 63;
  int lo = lane & 15, hi = lane >> 4;
  floatx4 acc[4] = {};
  const unsigned short* arow = Kt + ((size_t)b*MPAD + r0 + lo)*CC + hi*8;
#pragma unroll
  for (int k = 0; k < 8; ++k) {
    short8 af = ld8(arow + k*32);
#pragma unroll
    for (int t = 0; t < 4; ++t) {
      short8 bf = ld8(Bm + (size_t)(c0 + t*16 + lo)*CC + k*32 + hi*8);
      acc[t] = __builtin_amdgcn_mfma_f32_16x16x32_bf16(af, bf, acc[t], 0, 0, 0);
    }
  }
  if (mode == 0) {
#pragma unroll
    for (int t = 0; t < 4; ++t)
#pragma unroll
      for (int r = 0; r < 4; ++r) {
        int n = r0 + hi*4 + r, dd = c0 + t*16 + lo;
        Tout[((size_t)b*HWS + n)*CC + dd] = f2b(acc[t][r]);
      }
  } else {
#pragma unroll
    for (int t = 0; t < 4; ++t)
#pragma unroll
      for (int r = 0; r < 4; ++r) {
        int m = r0 + hi*4 + r, dd = c0 + t*16 + lo;
        Vbt[((size_t)b*CC + dd)*MPAD + m] = f2b(acc[t][r]);
      }
  }
}

// ---- reorder K and V into MFMA-fragment-major order, 1KB per instruction slot.
__global__ __launch_bounds__(256) void reorder_kv(const unsigned short* __restrict__ Kt,
    const unsigned short* __restrict__ Vbt, unsigned short* __restrict__ Kf,
    unsigned short* __restrict__ Vf) {
  int b = blockIdx.x, mt = blockIdx.y;
  int m0 = mt*64;
  int tid = threadIdx.x;
  int w = tid >> 6, lane = tid & 63;
  int lo = lane & 15, hi = lane >> 4;
  size_t tile = (size_t)(b*NTIL + mt)*16384;
  unsigned short* kf = Kf + tile;
  unsigned short* vf = Vf + tile;
  const unsigned short* ktb = Kt  + (size_t)b*MPAD*CC;
  const unsigned short* vtb = Vbt + (size_t)b*CC*MPAD;
#pragma unroll
  for (int i = 0; i < 8; ++i) {
    int s = i*4 + w;
    { // K slot
      int k = s >> 2, t = s & 3;
      short8 v = ld8(ktb + (size_t)(m0 + t*16 + lo)*CC + k*32 + hi*8);
      st8(kf + s*512 + lane*8, v);
    }
    { // V slot
      int h = s >> 4, t = s & 15;
      short8 v = ld8(vtb + (size_t)(t*16 + lo)*MPAD + m0 + h*32 + hi*8);
      st8(vf + s*512 + lane*8, v);
    }
  }
}

// ---- score mimicry of np/BLAS fp32 T-path, sequential FMA everywhere
__global__ __launch_bounds__(256) void scores_kernel(const float* __restrict__ img,
    const float* __restrict__ sim, const float* __restrict__ exe,
    float* __restrict__ score32) {
  int b = blockIdx.x, n0 = blockIdx.y*16;
  int d = threadIdx.x;
  __shared__ float U[16][257];        // U[nl][c] = img[b, c, n0+nl]
  __shared__ float R[16][256];        // T32[nl][d]
  __shared__ float E[256];
  for (int idx = threadIdx.x; idx < 16*256; idx += 256) {
    int nl = idx & 15, c = idx >> 4;
    U[nl][c] = img[((size_t)b*CC + c)*HWS + n0 + nl];
  }
  E[d] = 1.2f * exe[b*CC + d];
  __syncthreads();
  float acc[16];
#pragma unroll
  for (int nl = 0; nl < 16; ++nl) acc[nl] = 0.f;
  for (int c = 0; c < CC; ++c) {
    float s_cd = sim[c*CC + d];
#pragma unroll
    for (int nl = 0; nl < 16; ++nl) acc[nl] = fmaf(U[nl][c], s_cd, acc[nl]);
  }
#pragma unroll
  for (int nl = 0; nl < 16; ++nl) R[nl][d] = acc[nl];
  __syncthreads();
  if (d < 16) {
    float s = 0.f;
    for (int dd = 0; dd < CC; ++dd) s = fmaf(R[d][dd], E[dd], s);
    score32[b*HWS + n0 + d] = s;
  }
}

// ---- top-150 via exact radix-select on distinct 44-bit keys + bitonic-256 sort.
__global__ __launch_bounds__(64) void select_kernel(const float* __restrict__ scores,
                                                    int* __restrict__ qids) {
  int b = blockIdx.x, lane = threadIdx.x;
  __shared__ float sc[HWS];
  __shared__ unsigned long long kx[HWS];
  __shared__ unsigned long long list[256];
  __shared__ unsigned int hist[256];
  __shared__ unsigned int st[4];
  __shared__ unsigned long long sh_base;

  const floatx4* s4 = (const floatx4*)(scores + (size_t)b*HWS);
  floatx4* c4 = (floatx4*)sc;
#pragma unroll
  for (int i = 0; i < 16; ++i) c4[i*64 + lane] = s4[i*64 + lane];
  __syncthreads();

  for (int i = 0; i < 64; ++i) {
    int idx = i*64 + lane;
    int y = i, x = lane;
    float c0 = sc[idx];
    float v = c0;
    if (y >= 1 && y <= 62 && x >= 1 && x <= 62) {
      bool ismax = (c0 > sc[idx-64]) && (c0 >= sc[idx+64]) &&
                   (c0 > sc[idx-1])  && (c0 >= sc[idx+1]);
      if (!ismax) v = c0 - 1e9f;
    }
    unsigned u = __float_as_uint(v);
    u = (u & 0x80000000u) ? ~u : (u | 0x80000000u);
    kx[idx] = (((unsigned long long)u) << 12) | (unsigned long long)(4095 - idx);
  }
  __syncthreads();

  unsigned long long base = 0;
  unsigned int need = 150, C = 0;
  for (int s = 36; s >= 4; s -= 8) {
    for (int i = lane; i < 256; i += 64) hist[i] = 0;
    __syncthreads();
    unsigned long long pref = base >> (s + 8);
    for (int i = 0; i < 64; ++i) {
      unsigned long long k = kx[i*64 + lane];
      if ((k >> (s + 8)) == pref) atomicAdd(&hist[(unsigned)(k >> s) & 255u], 1u);
    }
    __syncthreads();
    if (lane == 0) {
      unsigned cum = 0; int B = 0;
      for (int bin = 255; bin >= 0; --bin) {
        cum += hist[bin];
        if (cum >= need) { B = bin; break; }
      }
      st[0] = (150u - need) + cum;
      st[1] = need - (cum - hist[B]);
      sh_base = base | ((unsigned long long)B << s);
    }
    __syncthreads();
    C = st[0]; need = st[1]; base = sh_base;
    if (C <= 256u) break;
  }

  if (lane == 0) st[2] = 0;
  __syncthreads();
  for (int i = 0; i < 64; ++i) {
    unsigned long long k = kx[i*64 + lane];
    if (k >= base) {
      unsigned p = atomicAdd(&st[2], 1u);
      list[p] = k;
    }
  }
  __syncthreads();
  for (int i = lane; i < 256; i += 64) if (i >= (int)C) list[i] = 0ull;
  __syncthreads();

  for (int kk = 2; kk <= 256; kk <<= 1) {
    for (int j = kk >> 1; j > 0; j >>= 1) {
#pragma unroll
      for (int tt = 0; tt < 2; ++tt) {
        int t = lane + tt*64;
        int i2 = ((t & ~(j - 1)) << 1) | (t & (j - 1));
        int p2 = i2 | j;
        bool desc = ((i2 & kk) == 0);
        unsigned long long a = list[i2], c = list[p2];
        bool sw = desc ? (a < c) : (a > c);
        if (sw) { list[i2] = c; list[p2] = a; }
      }
      __syncthreads();
    }
  }

  for (int q = lane; q < 150; q += 64)
    qids[b*150 + q] = 4095 - (int)(list[q] & 0xFFFull);
}

// ---- fused flash attention v9: v8's dual-row + KV-half-split (traffic /2)
//      with QUARTER-PHASE register streaming to stay under the 256-arch-VGPR
//      cap that spilled v8 (demand was 320 load-target regs -> 21MB scratch
//      writes, VGPR_Count=256). Two rotating 16-slot buffers X,Y (64 VGPR
//      each), one phase in flight ahead of consumption (16KB >> the ~3.5KB
//      needed to cover L2 latency at the per-wave BW share). Schedule/tile:
//      QK-A(X) -> issue vaA->X -> QK-B(Y) -> issue vaB->Y -> softmax ->
//      PV-A(X) -> issue kaA(mt+1)->X -> PV-B(Y) -> issue kaB(mt+1)->Y.
//      o0/o1 and s0/s1 are MFMA accumulators (AGPR file). Arch VGPR ~250.
//      Arithmetic identical to v8 (same MFMA order, same P path).
__global__ __launch_bounds__(256, 1) void flash_kernel(
    const unsigned short* __restrict__ Tb, const unsigned short* __restrict__ Kt,
    const unsigned short* __restrict__ Kf, const unsigned short* __restrict__ Vf,
    const float* __restrict__ mask, const float* __restrict__ colb,
    float* __restrict__ acc0, float* __restrict__ accH, float* __restrict__ lsums) {
  int blk = blockIdx.x;                       // 256 blocks
  int b    = (blk & 7) >> 1;                  // batch pinned to XCD pair
  int half = blk & 1;                         // KV half pinned to XCD
  int g    = blk >> 3;                        // row-group-128 [0,32)
  int tid = threadIdx.x;
  int wave = tid >> 6, lane = tid & 63;
  int lo = lane & 15, hi = lane >> 4;
  int n0 = g*128 + wave*32;                   // this wave's 32 Q-rows
  int t0 = half ? 33 : 0, t1 = half ? NTIL : 33;

  __shared__ unsigned short pbuf[4][1152];    // per-wave P / M-exchange
  unsigned short* plw = &pbuf[wave][0];

  // Q fragments for this wave's two row-groups
  short8 q0[8], q1[8];
  const unsigned short* tb0 = Tb + ((size_t)b*HWS + n0 + lo)*CC + hi*8;
#pragma unroll
  for (int k = 0; k < 8; ++k) { q0[k] = ld8(tb0 + k*32); q1[k] = ld8(tb0 + 16*CC + k*32); }

  const unsigned short* kfb = Kf + (size_t)b*NTIL*16384 + lane*8;
  const unsigned short* vfb = Vf + (size_t)b*NTIL*16384 + lane*8;

  // prologue staging: kaA(t0) -> X, kaB(t0) -> Y (overlaps prologue dots)
  short8 X[16], Y[16];
#pragma unroll
  for (int i = 0; i < 16; ++i) X[i] = ld8(kfb + (size_t)t0*16384 + i*512);
#pragma unroll
  for (int i = 0; i < 16; ++i) Y[i] = ld8(kfb + (size_t)t0*16384 + (16 + i)*512);

  const float* mk = mask + b*HWS;

  // ---- prologue: diag and exe dots (fp32), fixed row max M = pick + 2
  float crb0[4], Msub0[4], crb1[4], Msub1[4];
  {
    const unsigned short* kep = Kt + ((size_t)b*MPAD + HWS)*CC + hi*8;
    // row-group 0
    float ddot = 0.f, edot = 0.f;
    const unsigned short* kdp = Kt + ((size_t)b*MPAD + n0 + lo)*CC + hi*8;
#pragma unroll
    for (int k = 0; k < 8; ++k) {
      short8 kd = ld8(kdp + k*32);
      short8 ke = ld8(kep + k*32);
#pragma unroll
      for (int j = 0; j < 8; ++j) {
        float qf = b2f((unsigned short)q0[k][j]);
        ddot = fmaf(qf, b2f((unsigned short)kd[j]), ddot);
        edot = fmaf(qf, b2f((unsigned short)ke[j]), edot);
      }
    }
    ddot += __shfl_xor(ddot, 16); ddot += __shfl_xor(ddot, 32);
    edot += __shfl_xor(edot, 16); edot += __shfl_xor(edot, 32);
    float Mrow = ((mk[n0 + lo] == 1.0f) ? ddot : edot) + 2.0f;
    float* fM = (float*)plw;
    fM[lo] = Mrow;
#pragma unroll
    for (int r = 0; r < 4; ++r) {
      Msub0[r] = fM[hi*4 + r];
      crb0[r]  = (mk[n0 + hi*4 + r] - 1.0f)*1e9f - Msub0[r];
    }
    // row-group 1
    ddot = 0.f; edot = 0.f;
    const unsigned short* kdp1 = Kt + ((size_t)b*MPAD + n0 + 16 + lo)*CC + hi*8;
#pragma unroll
    for (int k = 0; k < 8; ++k) {
      short8 kd = ld8(kdp1 + k*32);
      short8 ke = ld8(kep + k*32);
#pragma unroll
      for (int j = 0; j < 8; ++j) {
        float qf = b2f((unsigned short)q1[k][j]);
        ddot = fmaf(qf, b2f((unsigned short)kd[j]), ddot);
        edot = fmaf(qf, b2f((unsigned short)ke[j]), edot);
      }
    }
    ddot += __shfl_xor(ddot, 16); ddot += __shfl_xor(ddot, 32);
    edot += __shfl_xor(edot, 16); edot += __shfl_xor(edot, 32);
    float Mrow1 = ((mk[n0 + 16 + lo] == 1.0f) ? ddot : edot) + 2.0f;
    fM[lo] = Mrow1;
#pragma unroll
    for (int r = 0; r < 4; ++r) {
      Msub1[r] = fM[hi*4 + r];
      crb1[r]  = (mk[n0 + 16 + hi*4 + r] - 1.0f)*1e9f - Msub1[r];
    }
  }

  float lsum0[4] = {0.f, 0.f, 0.f, 0.f};
  float lsum1[4] = {0.f, 0.f, 0.f, 0.f};
  floatx4 o0[16] = {};
  floatx4 o1[16] = {};
  const float* cbb = colb + b*MPAD;

  for (int mt = t0; mt < t1; ++mt) {
    int m0 = mt*64;
    const unsigned short* vs = vfb + (size_t)mt*16384;
    // ---- QK-A: K slots 0..15 (k=0..3) from X; each fragment feeds both groups
    floatx4 s0[4] = {}, s1[4] = {};
#pragma unroll
    for (int k = 0; k < 4; ++k)
#pragma unroll
      for (int t = 0; t < 4; ++t) {
        s0[t] = __builtin_amdgcn_mfma_f32_16x16x32_bf16(q0[k], X[k*4 + t], s0[t], 0, 0, 0);
        s1[t] = __builtin_amdgcn_mfma_f32_16x16x32_bf16(q1[k], X[k*4 + t], s1[t], 0, 0, 0);
      }
    // issue vaA(mt) -> X (X dead after QK-A)
#pragma unroll
    for (int i = 0; i < 16; ++i) X[i] = ld8(vs + i*512);
    // ---- QK-B: K slots 16..31 (k=4..7) from Y
#pragma unroll
    for (int k = 4; k < 8; ++k)
#pragma unroll
      for (int t = 0; t < 4; ++t) {
        s0[t] = __builtin_amdgcn_mfma_f32_16x16x32_bf16(q0[k], Y[(k-4)*4 + t], s0[t], 0, 0, 0);
        s1[t] = __builtin_amdgcn_mfma_f32_16x16x32_bf16(q1[k], Y[(k-4)*4 + t], s1[t], 0, 0, 0);
      }
    // issue vaB(mt) -> Y (Y dead after QK-B)
#pragma unroll
    for (int i = 0; i < 16; ++i) Y[i] = ld8(vs + (16 + i)*512);
    // ---- fixed-max softmax: p = exp(s + colb[m] + rowb[r] - M_r)
    float cb[4];
#pragma unroll
    for (int t = 0; t < 4; ++t) cb[t] = cbb[m0 + t*16 + lo];
    short8 pf00, pf01, pf10, pf11;
    { // row-group 0
      float pr[4][4];
#pragma unroll
      for (int t = 0; t < 4; ++t)
#pragma unroll
        for (int r = 0; r < 4; ++r)
          pr[t][r] = s0[t][r] + cb[t] + crb0[r];
      if (mt == NTIL-1 && lo == 0) {
        // exe column (m==4096, t==0): never row-masked -> drop rowb
#pragma unroll
        for (int r = 0; r < 4; ++r) pr[0][r] = s0[0][r] - Msub0[r];
      }
#pragma unroll
      for (int t = 0; t < 4; ++t)
#pragma unroll
        for (int r = 0; r < 4; ++r) {
          float p = __expf(pr[t][r]);
          lsum0[r] += p;
          plw[(hi*4 + r)*72 + t*16 + lo] = f2b(p);
        }
      pf00 = *(const short8*)&plw[lo*72 + hi*8];
      pf01 = *(const short8*)&plw[lo*72 + 32 + hi*8];
    }
    { // row-group 1
      float pr[4][4];
#pragma unroll
      for (int t = 0; t < 4; ++t)
#pragma unroll
        for (int r = 0; r < 4; ++r)
          pr[t][r] = s1[t][r] + cb[t] + crb1[r];
      if (mt == NTIL-1 && lo == 0) {
#pragma unroll
        for (int r = 0; r < 4; ++r) pr[0][r] = s1[0][r] - Msub1[r];
      }
#pragma unroll
      for (int t = 0; t < 4; ++t)
#pragma unroll
        for (int r = 0; r < 4; ++r) {
          float p = __expf(pr[t][r]);
          lsum1[r] += p;
          plw[(hi*4 + r)*72 + t*16 + lo] = f2b(p);
        }
      pf10 = *(const short8*)&plw[lo*72 + hi*8];
      pf11 = *(const short8*)&plw[lo*72 + 32 + hi*8];
    }
    // ---- PV-A: V slots 0..15 (m 0..31) from X
#pragma unroll
    for (int sl = 0; sl < 16; ++sl) {
      o0[sl] = __builtin_amdgcn_mfma_f32_16x16x32_bf16(pf00, X[sl], o0[sl], 0, 0, 0);
      o1[sl] = __builtin_amdgcn_mfma_f32_16x16x32_bf16(pf10, X[sl], o1[sl], 0, 0, 0);
    }
    // issue kaA(mt+1) -> X
    if (mt + 1 < t1) {
      const unsigned short* ks = kfb + (size_t)(mt+1)*16384;
#pragma unroll
      for (int i = 0; i < 16; ++i) X[i] = ld8(ks + i*512);
    }
    // ---- PV-B: V slots 16..31 (m 32..63) from Y
#pragma unroll
    for (int sl = 0; sl < 16; ++sl) {
      o0[sl] = __builtin_amdgcn_mfma_f32_16x16x32_bf16(pf01, Y[sl], o0[sl], 0, 0, 0);
      o1[sl] = __builtin_amdgcn_mfma_f32_16x16x32_bf16(pf11, Y[sl], o1[sl], 0, 0, 0);
    }
    // issue kaB(mt+1) -> Y
    if (mt + 1 < t1) {
      const unsigned short* ks = kfb + (size_t)(mt+1)*16384;
#pragma unroll
      for (int i = 0; i < 16; ++i) Y[i] = ld8(ks + (16 + i)*512);
    }
  }
  // ---- l reduction over the 16 lo lanes (both groups)
#pragma unroll
  for (int r = 0; r < 4; ++r) {
#pragma unroll
    for (int off = 1; off < 16; off <<= 1) {
      lsum0[r] += __shfl_xor(lsum0[r], off);
      lsum1[r] += __shfl_xor(lsum1[r], off);
    }
  }
  // ---- epilogue: scatter fp32 UNNORMALIZED partials (no rounding here)
  float* op = (half ? accH : acc0) + (size_t)b*CC*HWS;
#pragma unroll
  for (int t = 0; t < 16; ++t)
#pragma unroll
    for (int r = 0; r < 4; ++r) {
      op[(size_t)(t*16 + lo)*HWS + n0 + hi*4 + r]      = o0[t][r];
      op[(size_t)(t*16 + lo)*HWS + n0 + 16 + hi*4 + r] = o1[t][r];
    }
  if (lo == 0) {
    float* lp = lsums + ((size_t)(half*NB + b))*HWS;
#pragma unroll
    for (int r = 0; r < 4; ++r) {
      lp[n0 + hi*4 + r]      = lsum0[r];
      lp[n0 + 16 + hi*4 + r] = lsum1[r];
    }
  }
}

// ---- out0[b][d][n] = bf16_round( (p0+p1) * 1/(l0+l1) ) + img  (coalesced)
__global__ __launch_bounds__(256) void finalize_kernel(const float* __restrict__ accH,
    const float* __restrict__ lsums, const float* __restrict__ img,
    float* __restrict__ out0) {
  int b = blockIdx.x >> 8;
  int d = blockIdx.x & 255;
  size_t base = ((size_t)b*CC + d)*HWS;
  const float* l0 = lsums + (size_t)b*HWS;
  const float* l1 = lsums + (size_t)(NB + b)*HWS;
  for (int n = threadIdx.x; n < HWS; n += 256) {
    float inv = 1.0f / (l0[n] + l1[n]);
    float o = (out0[base + n] + accH[base + n]) * inv;
    out0[base + n] = b2f(f2b(o)) + img[base + n];
  }
}

// ---- queries[b][q][d] = sum_c img[b][c][id]*v_w[d][c]  (fp32 seq FMA)
__global__ __launch_bounds__(256) void gather_kernel(const float* __restrict__ img,
    const float* __restrict__ vw, const int* __restrict__ qids, float* __restrict__ out1) {
  int blk = blockIdx.x;
  int b = blk / 150, q = blk % 150;
  int dd = threadIdx.x;
  __shared__ float col[CC];
  int id = qids[b*150 + q];
  col[dd] = img[((size_t)b*CC + dd)*HWS + id];
  __syncthreads();
  const float* vr = vw + dd*CC;
  float acc = 0.f;
  for (int c = 0; c < CC; ++c) acc = fmaf(col[c], vr[c], acc);
  out1[((size_t)(b*150 + q))*CC + dd] = acc;
}

extern "C" void kernel_launch(void* const* d_in, const int* in_sizes, int n_in,
                              void* d_out, int out_size, void* d_ws, size_t ws_size,
                              hipStream_t stream) {
  const float* img  = (const float*)d_in[0];
  const float* exe  = (const float*)d_in[1];
  const float* mask = (const float*)d_in[2];
  const float* sim  = (const float*)d_in[3];
  const float* vw   = (const float*)d_in[4];
  float* out0 = (float*)d_out;
  float* out1 = out0 + (size_t)NB*CC*HWS;

  char* ws = (char*)d_ws;
  size_t o = 0;
  unsigned short* Kt  = (unsigned short*)(ws + o); o += (size_t)NB*MPAD*CC*2;
  unsigned short* Tb  = (unsigned short*)(ws + o); o += (size_t)NB*HWS*CC*2;
  unsigned short* Vbt = (unsigned short*)(ws + o); o += (size_t)NB*CC*MPAD*2;
  unsigned short* Kf  = (unsigned short*)(ws + o); o += (size_t)NB*NTIL*16384*2;
  unsigned short* Vf  = (unsigned short*)(ws + o); o += (size_t)NB*NTIL*16384*2;
  unsigned short* St  = (unsigned short*)(ws + o); o += (size_t)CC*CC*2;
  unsigned short* Vw  = (unsigned short*)(ws + o); o += (size_t)CC*CC*2;
  float*          scores = (float*)(ws + o);       o += (size_t)NB*HWS*4;
  float*          colb   = (float*)(ws + o);       o += (size_t)NB*MPAD*4;
  int*            qids   = (int*)(ws + o);         o += (size_t)NB*150*4;
  float*          accH   = (float*)(ws + o);       o += (size_t)NB*CC*HWS*4;
  float*          lsums  = (float*)(ws + o);       o += (size_t)2*NB*HWS*4;

  prep_mats  <<<dim3(CC),         dim3(CC),  0, stream>>>(sim, vw, St, Vw);
  colb_kernel<<<dim3(NB),         dim3(256), 0, stream>>>(mask, colb);
  build_kt   <<<dim3(NB, 65, 4),  dim3(256), 0, stream>>>(img, exe, Kt);
  gemm_small <<<dim3(NB, 64, 4),  dim3(256), 0, stream>>>(Kt, St, Tb, nullptr, 0);
  gemm_small <<<dim3(NB, 65, 4),  dim3(256), 0, stream>>>(Kt, Vw, nullptr, Vbt, 1);
  reorder_kv <<<dim3(NB, NTIL),   dim3(256), 0, stream>>>(Kt, Vbt, Kf, Vf);
  scores_kernel<<<dim3(NB, 256),  dim3(256), 0, stream>>>(img, sim, exe, scores);
  select_kernel<<<dim3(NB),       dim3(64),  0, stream>>>(scores, qids);
  flash_kernel <<<dim3(256),      dim3(256), 0, stream>>>(Tb, Kt, Kf, Vf, mask, colb,
                                                          out0, accH, lsums);
  finalize_kernel<<<dim3(NB*CC),  dim3(256), 0, stream>>>(accH, lsums, img, out0);
  gather_kernel<<<dim3(NB*150),   dim3(256), 0, stream>>>(img, vw, qids, out1);
}

// Round 6
// 375.448 us; speedup vs baseline: 1.3889x; 1.0274x over previous
//
#include <hip/hip_runtime.h>

#define CC   256
#define HWS  4096
#define MPAD 4160   // 65*64, rows >= 4097 zero-padded
#define NB   4
#define NTIL 65

typedef __attribute__((ext_vector_type(8))) short   short8;
typedef __attribute__((ext_vector_type(4))) float   floatx4;

static __device__ __forceinline__ short8 ld8(const unsigned short* p) {
  return *(const short8*)p;
}
static __device__ __forceinline__ void st8(unsigned short* p, short8 v) {
  *(short8*)p = v;
}
static __device__ __forceinline__ unsigned short f2b(float x) {
  union { float f; unsigned u; } v; v.f = x;
  unsigned r = v.u + 0x7FFFu + ((v.u >> 16) & 1u);
  return (unsigned short)(r >> 16);
}
static __device__ __forceinline__ float b2f(unsigned short x) {
  union { unsigned u; float f; } v; v.u = ((unsigned)x) << 16;
  return v.f;
}

// ---- merged: St[d][c] = sim[c][d], Vw[d][c] = v_w[d][c] (bf16); colb biases
__global__ void prep_colb(const float* __restrict__ sim, const float* __restrict__ vw,
                          const float* __restrict__ mask,
                          unsigned short* __restrict__ St, unsigned short* __restrict__ Vw,
                          float* __restrict__ colb) {
  int blk = blockIdx.x, tid = threadIdx.x;
  if (blk < CC) {
    int dd = blk, c = tid;
    St[dd*CC + c] = f2b(sim[c*CC + dd]);
    Vw[dd*CC + c] = f2b(vw[dd*CC + c]);
    return;
  }
  int b = blk - CC;
  for (int m = tid; m < MPAD; m += 256) {
    float v;
    if (m < HWS)      v = (mask[b*HWS + m] - 1.0f) * 1e9f;
    else if (m == HWS) v = 0.0f;
    else               v = -3.0e38f;
    colb[b*MPAD + m] = v;
  }
}

// ---- Kt[b][m][d] = bf16(concat[b][d][m]); ALSO writes Kf fragment-major
//      directly (replaces reorder_kv's K half): Kf[tile][s*512+lane*8+j] =
//      Kt[(m0+t*16+lo)*CC + k*32+hi*8+j], s=k*4+t. Block (b,mt,dt) owns
//      k in {2dt,2dt+1} -> slots 8dt..8dt+7, 2 per wave-lane-thread.
__global__ void build_kt(const float* __restrict__ img, const float* __restrict__ exe,
                         unsigned short* __restrict__ Kt, unsigned short* __restrict__ Kf) {
  int b = blockIdx.x, mt = blockIdx.y, dt = blockIdx.z;
  int tid = threadIdx.x;
  int m0 = mt*64, d0 = dt*64;
  int w = tid >> 6, lane = tid & 63, lo = lane & 15, hi = lane >> 4;
  unsigned short* kft = Kf + (size_t)(b*NTIL + mt)*16384;
  if (mt == 64) {
    for (int i = 0; i < 16; ++i) {
      int m = m0 + (tid>>6) + i*4;
      int d = d0 + (tid&63);
      unsigned short v = 0;
      if (m == 4096) v = f2b(1.2f * exe[b*CC + d]);
      Kt[((size_t)b*MPAD + m)*CC + d] = v;
    }
#pragma unroll
    for (int ss = 0; ss < 2; ++ss) {
      int s = dt*8 + w*2 + ss;
      int k = s >> 2, t = s & 3;
      unsigned short tmp[8] = {0,0,0,0,0,0,0,0};
      if (t == 0 && lo == 0) {
#pragma unroll
        for (int j = 0; j < 8; ++j)
          tmp[j] = f2b(1.2f * exe[b*CC + k*32 + hi*8 + j]);
      }
      st8(kft + s*512 + lane*8, *(short8*)tmp);
    }
    return;
  }
  __shared__ float tile[64][65];
  for (int i = 0; i < 16; ++i) {
    int dl = (tid>>6) + i*4, ml = tid&63;
    tile[dl][ml] = img[((size_t)b*CC + d0+dl)*HWS + m0+ml];
  }
  __syncthreads();
  for (int i = 0; i < 16; ++i) {
    int ml = (tid>>6) + i*4, dl = tid&63;
    Kt[((size_t)b*MPAD + m0+ml)*CC + d0+dl] = f2b(tile[dl][ml]);
  }
#pragma unroll
  for (int ss = 0; ss < 2; ++ss) {
    int s = dt*8 + w*2 + ss;
    int k = s >> 2, t = s & 3;
    int ml = t*16 + lo;
    int dlb = (k - dt*2)*32 + hi*8;
    unsigned short tmp[8];
#pragma unroll
    for (int j = 0; j < 8; ++j) tmp[j] = f2b(tile[dlb + j][ml]);
    st8(kft + s*512 + lane*8, *(short8*)tmp);
  }
}

// ---- mode 0: Tb[b][n][d] = bf16( sum_c Kt[n][c]*St[d][c] )          (rows < HWS)
// ---- mode 1: Vf fragment-major = bf16( sum_c Kt[m][c]*Vw[d][c] )    (rows < MPAD)
//      (mode 1 scatters directly into Vf: replaces reorder_kv's V half + Vbt)
__global__ __launch_bounds__(256) void gemm_small(const unsigned short* __restrict__ Kt,
    const unsigned short* __restrict__ Bm, unsigned short* __restrict__ Tout,
    unsigned short* __restrict__ Vf, int mode) {
  int b  = blockIdx.x;
  int r0 = blockIdx.y*64 + (threadIdx.x>>6)*16;
  int c0 = blockIdx.z*64;
  int lane = threadIdx.x & 63;
  int lo = lane & 15, hi = lane >> 4;
  floatx4 acc[4] = {};
  const unsigned short* arow = Kt + ((size_t)b*MPAD + r0 + lo)*CC + hi*8;
#pragma unroll
  for (int k = 0; k < 8; ++k) {
    short8 af = ld8(arow + k*32);
#pragma unroll
    for (int t = 0; t < 4; ++t) {
      short8 bf = ld8(Bm + (size_t)(c0 + t*16 + lo)*CC + k*32 + hi*8);
      acc[t] = __builtin_amdgcn_mfma_f32_16x16x32_bf16(af, bf, acc[t], 0, 0, 0);
    }
  }
  if (mode == 0) {
#pragma unroll
    for (int t = 0; t < 4; ++t)
#pragma unroll
      for (int r = 0; r < 4; ++r) {
        int n = r0 + hi*4 + r, dd = c0 + t*16 + lo;
        Tout[((size_t)b*HWS + n)*CC + dd] = f2b(acc[t][r]);
      }
  } else {
    unsigned short* vfb = Vf + (size_t)b*NTIL*16384;
#pragma unroll
    for (int t = 0; t < 4; ++t)
#pragma unroll
      for (int r = 0; r < 4; ++r) {
        int m = r0 + hi*4 + r, dd = c0 + t*16 + lo;
        int mt = m >> 6, ml = m & 63;
        int h = ml >> 5, im = ml & 31;
        int s = h*16 + (dd >> 4);
        int lane2 = (im >> 3)*16 + lo;
        int j = im & 7;
        vfb[(size_t)mt*16384 + s*512 + lane2*8 + j] = f2b(acc[t][r]);
      }
  }
}

// ---- score mimicry of np/BLAS fp32 T-path, sequential FMA everywhere.
//      32 rows/block (halves sim re-reads); R padded to 257 (bank-conflict-free
//      phase 2). Per-row arithmetic identical to the 16-row version.
__global__ __launch_bounds__(256) void scores_kernel(const float* __restrict__ img,
    const float* __restrict__ sim, const float* __restrict__ exe,
    float* __restrict__ score32) {
  int b = blockIdx.x, n0 = blockIdx.y*32;
  int d = threadIdx.x;
  __shared__ float U[32][257];        // U[nl][c] = img[b, c, n0+nl]
  __shared__ float R[32][257];        // T32[nl][d]
  __shared__ float E[256];
  for (int idx = threadIdx.x; idx < 32*256; idx += 256) {
    int nl = idx & 31, c = idx >> 5;
    U[nl][c] = img[((size_t)b*CC + c)*HWS + n0 + nl];
  }
  E[d] = 1.2f * exe[b*CC + d];
  __syncthreads();
  float acc[32];
#pragma unroll
  for (int nl = 0; nl < 32; ++nl) acc[nl] = 0.f;
  for (int c = 0; c < CC; ++c) {
    float s_cd = sim[c*CC + d];
#pragma unroll
    for (int nl = 0; nl < 32; ++nl) acc[nl] = fmaf(U[nl][c], s_cd, acc[nl]);
  }
#pragma unroll
  for (int nl = 0; nl < 32; ++nl) R[nl][d] = acc[nl];
  __syncthreads();
  if (d < 32) {
    float s = 0.f;
    for (int dd = 0; dd < CC; ++dd) s = fmaf(R[d][dd], E[dd], s);
    score32[b*HWS + n0 + d] = s;
  }
}

// ---- top-150 via exact radix-select on distinct 44-bit keys + bitonic-256 sort.
__global__ __launch_bounds__(64) void select_kernel(const float* __restrict__ scores,
                                                    int* __restrict__ qids) {
  int b = blockIdx.x, lane = threadIdx.x;
  __shared__ float sc[HWS];
  __shared__ unsigned long long kx[HWS];
  __shared__ unsigned long long list[256];
  __shared__ unsigned int hist[256];
  __shared__ unsigned int st[4];
  __shared__ unsigned long long sh_base;

  const floatx4* s4 = (const floatx4*)(scores + (size_t)b*HWS);
  floatx4* c4 = (floatx4*)sc;
#pragma unroll
  for (int i = 0; i < 16; ++i) c4[i*64 + lane] = s4[i*64 + lane];
  __syncthreads();

  for (int i = 0; i < 64; ++i) {
    int idx = i*64 + lane;
    int y = i, x = lane;
    float c0 = sc[idx];
    float v = c0;
    if (y >= 1 && y <= 62 && x >= 1 && x <= 62) {
      bool ismax = (c0 > sc[idx-64]) && (c0 >= sc[idx+64]) &&
                   (c0 > sc[idx-1])  && (c0 >= sc[idx+1]);
      if (!ismax) v = c0 - 1e9f;
    }
    unsigned u = __float_as_uint(v);
    u = (u & 0x80000000u) ? ~u : (u | 0x80000000u);
    kx[idx] = (((unsigned long long)u) << 12) | (unsigned long long)(4095 - idx);
  }
  __syncthreads();

  unsigned long long base = 0;
  unsigned int need = 150, C = 0;
  for (int s = 36; s >= 4; s -= 8) {
    for (int i = lane; i < 256; i += 64) hist[i] = 0;
    __syncthreads();
    unsigned long long pref = base >> (s + 8);
    for (int i = 0; i < 64; ++i) {
      unsigned long long k = kx[i*64 + lane];
      if ((k >> (s + 8)) == pref) atomicAdd(&hist[(unsigned)(k >> s) & 255u], 1u);
    }
    __syncthreads();
    if (lane == 0) {
      unsigned cum = 0; int B = 0;
      for (int bin = 255; bin >= 0; --bin) {
        cum += hist[bin];
        if (cum >= need) { B = bin; break; }
      }
      st[0] = (150u - need) + cum;
      st[1] = need - (cum - hist[B]);
      sh_base = base | ((unsigned long long)B << s);
    }
    __syncthreads();
    C = st[0]; need = st[1]; base = sh_base;
    if (C <= 256u) break;
  }

  if (lane == 0) st[2] = 0;
  __syncthreads();
  for (int i = 0; i < 64; ++i) {
    unsigned long long k = kx[i*64 + lane];
    if (k >= base) {
      unsigned p = atomicAdd(&st[2], 1u);
      list[p] = k;
    }
  }
  __syncthreads();
  for (int i = lane; i < 256; i += 64) if (i >= (int)C) list[i] = 0ull;
  __syncthreads();

  for (int kk = 2; kk <= 256; kk <<= 1) {
    for (int j = kk >> 1; j > 0; j >>= 1) {
#pragma unroll
      for (int tt = 0; tt < 2; ++tt) {
        int t = lane + tt*64;
        int i2 = ((t & ~(j - 1)) << 1) | (t & (j - 1));
        int p2 = i2 | j;
        bool desc = ((i2 & kk) == 0);
        unsigned long long a = list[i2], c = list[p2];
        bool sw = desc ? (a < c) : (a > c);
        if (sw) { list[i2] = c; list[p2] = a; }
      }
      __syncthreads();
    }
  }

  for (int q = lane; q < 150; q += 64)
    qids[b*150 + q] = 4095 - (int)(list[q] & 0xFFFull);
}

// ---- fused flash attention v9 (UNCHANGED from round 5: proven 115.5us).
//      Dual 16-row groups per wave + KV-half split + quarter-phase register
//      streaming (X/Y 16-slot rotating buffers, one phase in flight).
__global__ __launch_bounds__(256, 1) void flash_kernel(
    const unsigned short* __restrict__ Tb, const unsigned short* __restrict__ Kt,
    const unsigned short* __restrict__ Kf, const unsigned short* __restrict__ Vf,
    const float* __restrict__ mask, const float* __restrict__ colb,
    float* __restrict__ acc0, float* __restrict__ accH, float* __restrict__ lsums) {
  int blk = blockIdx.x;                       // 256 blocks
  int b    = (blk & 7) >> 1;                  // batch pinned to XCD pair
  int half = blk & 1;                         // KV half pinned to XCD
  int g    = blk >> 3;                        // row-group-128 [0,32)
  int tid = threadIdx.x;
  int wave = tid >> 6, lane = tid & 63;
  int lo = lane & 15, hi = lane >> 4;
  int n0 = g*128 + wave*32;                   // this wave's 32 Q-rows
  int t0 = half ? 33 : 0, t1 = half ? NTIL : 33;

  __shared__ unsigned short pbuf[4][1152];    // per-wave P / M-exchange
  unsigned short* plw = &pbuf[wave][0];

  // Q fragments for this wave's two row-groups
  short8 q0[8], q1[8];
  const unsigned short* tb0 = Tb + ((size_t)b*HWS + n0 + lo)*CC + hi*8;
#pragma unroll
  for (int k = 0; k < 8; ++k) { q0[k] = ld8(tb0 + k*32); q1[k] = ld8(tb0 + 16*CC + k*32); }

  const unsigned short* kfb = Kf + (size_t)b*NTIL*16384 + lane*8;
  const unsigned short* vfb = Vf + (size_t)b*NTIL*16384 + lane*8;

  // prologue staging: kaA(t0) -> X, kaB(t0) -> Y (overlaps prologue dots)
  short8 X[16], Y[16];
#pragma unroll
  for (int i = 0; i < 16; ++i) X[i] = ld8(kfb + (size_t)t0*16384 + i*512);
#pragma unroll
  for (int i = 0; i < 16; ++i) Y[i] = ld8(kfb + (size_t)t0*16384 + (16 + i)*512);

  const float* mk = mask + b*HWS;

  // ---- prologue: diag and exe dots (fp32), fixed row max M = pick + 2
  float crb0[4], Msub0[4], crb1[4], Msub1[4];
  {
    const unsigned short* kep = Kt + ((size_t)b*MPAD + HWS)*CC + hi*8;
    // row-group 0
    float ddot = 0.f, edot = 0.f;
    const unsigned short* kdp = Kt + ((size_t)b*MPAD + n0 + lo)*CC + hi*8;
#pragma unroll
    for (int k = 0; k < 8; ++k) {
      short8 kd = ld8(kdp + k*32);
      short8 ke = ld8(kep + k*32);
#pragma unroll
      for (int j = 0; j < 8; ++j) {
        float qf = b2f((unsigned short)q0[k][j]);
        ddot = fmaf(qf, b2f((unsigned short)kd[j]), ddot);
        edot = fmaf(qf, b2f((unsigned short)ke[j]), edot);
      }
    }
    ddot += __shfl_xor(ddot, 16); ddot += __shfl_xor(ddot, 32);
    edot += __shfl_xor(edot, 16); edot += __shfl_xor(edot, 32);
    float Mrow = ((mk[n0 + lo] == 1.0f) ? ddot : edot) + 2.0f;
    float* fM = (float*)plw;
    fM[lo] = Mrow;
#pragma unroll
    for (int r = 0; r < 4; ++r) {
      Msub0[r] = fM[hi*4 + r];
      crb0[r]  = (mk[n0 + hi*4 + r] - 1.0f)*1e9f - Msub0[r];
    }
    // row-group 1
    ddot = 0.f; edot = 0.f;
    const unsigned short* kdp1 = Kt + ((size_t)b*MPAD + n0 + 16 + lo)*CC + hi*8;
#pragma unroll
    for (int k = 0; k < 8; ++k) {
      short8 kd = ld8(kdp1 + k*32);
      short8 ke = ld8(kep + k*32);
#pragma unroll
      for (int j = 0; j < 8; ++j) {
        float qf = b2f((unsigned short)q1[k][j]);
        ddot = fmaf(qf, b2f((unsigned short)kd[j]), ddot);
        edot = fmaf(qf, b2f((unsigned short)ke[j]), edot);
      }
    }
    ddot += __shfl_xor(ddot, 16); ddot += __shfl_xor(ddot, 32);
    edot += __shfl_xor(edot, 16); edot += __shfl_xor(edot, 32);
    float Mrow1 = ((mk[n0 + 16 + lo] == 1.0f) ? ddot : edot) + 2.0f;
    fM[lo] = Mrow1;
#pragma unroll
    for (int r = 0; r < 4; ++r) {
      Msub1[r] = fM[hi*4 + r];
      crb1[r]  = (mk[n0 + 16 + hi*4 + r] - 1.0f)*1e9f - Msub1[r];
    }
  }

  float lsum0[4] = {0.f, 0.f, 0.f, 0.f};
  float lsum1[4] = {0.f, 0.f, 0.f, 0.f};
  floatx4 o0[16] = {};
  floatx4 o1[16] = {};
  const float* cbb = colb + b*MPAD;

  for (int mt = t0; mt < t1; ++mt) {
    int m0 = mt*64;
    const unsigned short* vs = vfb + (size_t)mt*16384;
    // ---- QK-A: K slots 0..15 (k=0..3) from X; each fragment feeds both groups
    floatx4 s0[4] = {}, s1[4] = {};
#pragma unroll
    for (int k = 0; k < 4; ++k)
#pragma unroll
      for (int t = 0; t < 4; ++t) {
        s0[t] = __builtin_amdgcn_mfma_f32_16x16x32_bf16(q0[k], X[k*4 + t], s0[t], 0, 0, 0);
        s1[t] = __builtin_amdgcn_mfma_f32_16x16x32_bf16(q1[k], X[k*4 + t], s1[t], 0, 0, 0);
      }
    // issue vaA(mt) -> X (X dead after QK-A)
#pragma unroll
    for (int i = 0; i < 16; ++i) X[i] = ld8(vs + i*512);
    // ---- QK-B: K slots 16..31 (k=4..7) from Y
#pragma unroll
    for (int k = 4; k < 8; ++k)
#pragma unroll
      for (int t = 0; t < 4; ++t) {
        s0[t] = __builtin_amdgcn_mfma_f32_16x16x32_bf16(q0[k], Y[(k-4)*4 + t], s0[t], 0, 0, 0);
        s1[t] = __builtin_amdgcn_mfma_f32_16x16x32_bf16(q1[k], Y[(k-4)*4 + t], s1[t], 0, 0, 0);
      }
    // issue vaB(mt) -> Y (Y dead after QK-B)
#pragma unroll
    for (int i = 0; i < 16; ++i) Y[i] = ld8(vs + (16 + i)*512);
    // ---- fixed-max softmax: p = exp(s + colb[m] + rowb[r] - M_r)
    float cb[4];
#pragma unroll
    for (int t = 0; t < 4; ++t) cb[t] = cbb[m0 + t*16 + lo];
    short8 pf00, pf01, pf10, pf11;
    { // row-group 0
      float pr[4][4];
#pragma unroll
      for (int t = 0; t < 4; ++t)
#pragma unroll
        for (int r = 0; r < 4; ++r)
          pr[t][r] = s0[t][r] + cb[t] + crb0[r];
      if (mt == NTIL-1 && lo == 0) {
        // exe column (m==4096, t==0): never row-masked -> drop rowb
#pragma unroll
        for (int r = 0; r < 4; ++r) pr[0][r] = s0[0][r] - Msub0[r];
      }
#pragma unroll
      for (int t = 0; t < 4; ++t)
#pragma unroll
        for (int r = 0; r < 4; ++r) {
          float p = __expf(pr[t][r]);
          lsum0[r] += p;
          plw[(hi*4 + r)*72 + t*16 + lo] = f2b(p);
        }
      pf00 = *(const short8*)&plw[lo*72 + hi*8];
      pf01 = *(const short8*)&plw[lo*72 + 32 + hi*8];
    }
    { // row-group 1
      float pr[4][4];
#pragma unroll
      for (int t = 0; t < 4; ++t)
#pragma unroll
        for (int r = 0; r < 4; ++r)
          pr[t][r] = s1[t][r] + cb[t] + crb1[r];
      if (mt == NTIL-1 && lo == 0) {
#pragma unroll
        for (int r = 0; r < 4; ++r) pr[0][r] = s1[0][r] - Msub1[r];
      }
#pragma unroll
      for (int t = 0; t < 4; ++t)
#pragma unroll
        for (int r = 0; r < 4; ++r) {
          float p = __expf(pr[t][r]);
          lsum1[r] += p;
          plw[(hi*4 + r)*72 + t*16 + lo] = f2b(p);
        }
      pf10 = *(const short8*)&plw[lo*72 + hi*8];
      pf11 = *(const short8*)&plw[lo*72 + 32 + hi*8];
    }
    // ---- PV-A: V slots 0..15 (m 0..31) from X
#pragma unroll
    for (int sl = 0; sl < 16; ++sl) {
      o0[sl] = __builtin_amdgcn_mfma_f32_16x16x32_bf16(pf00, X[sl], o0[sl], 0, 0, 0);
      o1[sl] = __builtin_amdgcn_mfma_f32_16x16x32_bf16(pf10, X[sl], o1[sl], 0, 0, 0);
    }
    // issue kaA(mt+1) -> X
    if (mt + 1 < t1) {
      const unsigned short* ks = kfb + (size_t)(mt+1)*16384;
#pragma unroll
      for (int i = 0; i < 16; ++i) X[i] = ld8(ks + i*512);
    }
    // ---- PV-B: V slots 16..31 (m 32..63) from Y
#pragma unroll
    for (int sl = 0; sl < 16; ++sl) {
      o0[sl] = __builtin_amdgcn_mfma_f32_16x16x32_bf16(pf01, Y[sl], o0[sl], 0, 0, 0);
      o1[sl] = __builtin_amdgcn_mfma_f32_16x16x32_bf16(pf11, Y[sl], o1[sl], 0, 0, 0);
    }
    // issue kaB(mt+1) -> Y
    if (mt + 1 < t1) {
      const unsigned short* ks = kfb + (size_t)(mt+1)*16384;
#pragma unroll
      for (int i = 0; i < 16; ++i) Y[i] = ld8(ks + (16 + i)*512);
    }
  }
  // ---- l reduction over the 16 lo lanes (both groups)
#pragma unroll
  for (int r = 0; r < 4; ++r) {
#pragma unroll
    for (int off = 1; off < 16; off <<= 1) {
      lsum0[r] += __shfl_xor(lsum0[r], off);
      lsum1[r] += __shfl_xor(lsum1[r], off);
    }
  }
  // ---- epilogue: scatter fp32 UNNORMALIZED partials (no rounding here)
  float* op = (half ? accH : acc0) + (size_t)b*CC*HWS;
#pragma unroll
  for (int t = 0; t < 16; ++t)
#pragma unroll
    for (int r = 0; r < 4; ++r) {
      op[(size_t)(t*16 + lo)*HWS + n0 + hi*4 + r]      = o0[t][r];
      op[(size_t)(t*16 + lo)*HWS + n0 + 16 + hi*4 + r] = o1[t][r];
    }
  if (lo == 0) {
    float* lp = lsums + ((size_t)(half*NB + b))*HWS;
#pragma unroll
    for (int r = 0; r < 4; ++r) {
      lp[n0 + hi*4 + r]      = lsum0[r];
      lp[n0 + 16 + hi*4 + r] = lsum1[r];
    }
  }
}

// ---- out0[b][d][n] = bf16_round( (p0+p1) * 1/(l0+l1) ) + img  (coalesced)
__global__ __launch_bounds__(256) void finalize_kernel(const float* __restrict__ accH,
    const float* __restrict__ lsums, const float* __restrict__ img,
    float* __restrict__ out0) {
  int b = blockIdx.x >> 8;
  int d = blockIdx.x & 255;
  size_t base = ((size_t)b*CC + d)*HWS;
  const float* l0 = lsums + (size_t)b*HWS;
  const float* l1 = lsums + (size_t)(NB + b)*HWS;
  for (int n = threadIdx.x; n < HWS; n += 256) {
    float inv = 1.0f / (l0[n] + l1[n]);
    float o = (out0[base + n] + accH[base + n]) * inv;
    out0[base + n] = b2f(f2b(o)) + img[base + n];
  }
}

// ---- queries[b][q][d] = sum_c img[b][c][id]*v_w[d][c]  (fp32 seq FMA)
__global__ __launch_bounds__(256) void gather_kernel(const float* __restrict__ img,
    const float* __restrict__ vw, const int* __restrict__ qids, float* __restrict__ out1) {
  int blk = blockIdx.x;
  int b = blk / 150, q = blk % 150;
  int dd = threadIdx.x;
  __shared__ float col[CC];
  int id = qids[b*150 + q];
  col[dd] = img[((size_t)b*CC + dd)*HWS + id];
  __syncthreads();
  const float* vr = vw + dd*CC;
  float acc = 0.f;
  for (int c = 0; c < CC; ++c) acc = fmaf(col[c], vr[c], acc);
  out1[((size_t)(b*150 + q))*CC + dd] = acc;
}

extern "C" void kernel_launch(void* const* d_in, const int* in_sizes, int n_in,
                              void* d_out, int out_size, void* d_ws, size_t ws_size,
                              hipStream_t stream) {
  const float* img  = (const float*)d_in[0];
  const float* exe  = (const float*)d_in[1];
  const float* mask = (const float*)d_in[2];
  const float* sim  = (const float*)d_in[3];
  const float* vw   = (const float*)d_in[4];
  float* out0 = (float*)d_out;
  float* out1 = out0 + (size_t)NB*CC*HWS;

  char* ws = (char*)d_ws;
  size_t o = 0;
  unsigned short* Kt  = (unsigned short*)(ws + o); o += (size_t)NB*MPAD*CC*2;
  unsigned short* Tb  = (unsigned short*)(ws + o); o += (size_t)NB*HWS*CC*2;
  unsigned short* Kf  = (unsigned short*)(ws + o); o += (size_t)NB*NTIL*16384*2;
  unsigned short* Vf  = (unsigned short*)(ws + o); o += (size_t)NB*NTIL*16384*2;
  unsigned short* St  = (unsigned short*)(ws + o); o += (size_t)CC*CC*2;
  unsigned short* Vw  = (unsigned short*)(ws + o); o += (size_t)CC*CC*2;
  float*          scores = (float*)(ws + o);       o += (size_t)NB*HWS*4;
  float*          colb   = (float*)(ws + o);       o += (size_t)NB*MPAD*4;
  int*            qids   = (int*)(ws + o);         o += (size_t)NB*150*4;
  float*          accH   = (float*)(ws + o);       o += (size_t)NB*CC*HWS*4;
  float*          lsums  = (float*)(ws + o);       o += (size_t)2*NB*HWS*4;

  prep_colb  <<<dim3(CC + NB),    dim3(256), 0, stream>>>(sim, vw, mask, St, Vw, colb);
  build_kt   <<<dim3(NB, 65, 4),  dim3(256), 0, stream>>>(img, exe, Kt, Kf);
  gemm_small <<<dim3(NB, 64, 4),  dim3(256), 0, stream>>>(Kt, St, Tb, nullptr, 0);
  gemm_small <<<dim3(NB, 65, 4),  dim3(256), 0, stream>>>(Kt, Vw, nullptr, Vf, 1);
  scores_kernel<<<dim3(NB, 128),  dim3(256), 0, stream>>>(img, sim, exe, scores);
  select_kernel<<<dim3(NB),       dim3(64),  0, stream>>>(scores, qids);
  flash_kernel <<<dim3(256),      dim3(256), 0, stream>>>(Tb, Kt, Kf, Vf, mask, colb,
                                                          out0, accH, lsums);
  finalize_kernel<<<dim3(NB*CC),  dim3(256), 0, stream>>>(accH, lsums, img, out0);
  gather_kernel<<<dim3(NB*150),   dim3(256), 0, stream>>>(img, vw, qids, out1);
}